// Round 13
// baseline (145.291 us; speedup 1.0000x reference)
//
#include <hip/hip_runtime.h>

typedef _Float16 f16;
typedef _Float16 f16x8 __attribute__((ext_vector_type(8)));
typedef float f32x4 __attribute__((ext_vector_type(4)));

#define NEG_INF_F (-1e10f)

__device__ __forceinline__ void stage16(const f16* g, f16* l) {
    __builtin_amdgcn_global_load_lds((const __attribute__((address_space(1))) void*)g,
                                     (__attribute__((address_space(3))) void*)l, 16, 0, 0);
}

// ---------------- prep: me_h + weight transposes + class_labels pad ----------
__global__ __launch_bounds__(256) void prep(const float* __restrict__ me,
                                            const float* __restrict__ mw1,
                                            const float* __restrict__ vw1,
                                            const float* __restrict__ mw2,
                                            const float* __restrict__ vw2,
                                            const float* __restrict__ aw1,
                                            const float* __restrict__ cl,
                                            f16* __restrict__ me_h,
                                            f16* __restrict__ mw1t, f16* __restrict__ vw1t,
                                            f16* __restrict__ mw2t, f16* __restrict__ vw2t,
                                            f16* __restrict__ aw1t, f16* __restrict__ cl_h) {
    int i = blockIdx.x * 256 + threadIdx.x;
    if (i < 2097152) {
        me_h[i] = (f16)me[i];
        return;
    }
    int j = i - 2097152;
    if (j < 1048576) {
        int seg = j >> 19;
        int jj = j & 524287;
        int k = jj & 1023, n = jj >> 10;
        if (seg == 0) mw1t[n * 1024 + k] = (f16)mw1[k * 512 + n];
        else          vw1t[n * 1024 + k] = (k < 1000) ? (f16)vw1[k * 512 + n] : (f16)0.f;
        return;
    }
    j -= 1048576;
    if (j < 786432) {
        int seg = j >> 18;
        int r = j & 262143;
        int k = r & 511, n = r >> 9;
        const float* src = (seg == 0) ? mw2 : (seg == 1) ? vw2 : aw1;
        f16* dst = (seg == 0) ? mw2t : (seg == 1) ? vw2t : aw1t;
        dst[n * 512 + k] = (f16)src[k * 512 + n];
        return;
    }
    j -= 786432;
    int r = j >> 10, k = j & 1023;
    cl_h[j] = (k < 1000) ? (f16)cl[r * 1000 + k] : (f16)0.f;
}

// ---------------- staged 1-wave GEMM: out = act(A @ Wt^T + bias), 32x32 tile ----------
__global__ __launch_bounds__(64) void gemm_stg(const f16* __restrict__ Am,
                                               const f16* __restrict__ Av,
                                               const f16* __restrict__ Wm,
                                               const f16* __restrict__ Wv,
                                               const float* __restrict__ bm,
                                               const float* __restrict__ bv,
                                               f16* __restrict__ om,
                                               f16* __restrict__ ov,
                                               int K, int relu) {
    __shared__ f16 ab[2][1024], bb[2][1024];  // [buf][row 0..31][unit 0..3][8 f16]

    int t = threadIdx.x;
    int rl = t & 15, kg = t >> 4;
    bool isv = blockIdx.x >= 64;
    int mb = isv ? blockIdx.x - 64 : blockIdx.x;
    const f16* A = isv ? Av : Am;
    const f16* Wt = isv ? Wv : Wm;
    const float* bias = isv ? bv : bm;
    f16* out = isv ? ov : om;
    int m0 = mb * 32, n0 = blockIdx.y * 32;
    int pu = kg ^ ((rl >> 1) & 3);

    int srow = t >> 2;
    int sk8 = (t & 3) ^ ((srow >> 1) & 3);
    const f16* a_src = A + (m0 + srow) * K + sk8 * 8;
    const f16* b_src = Wt + (n0 + srow) * K + sk8 * 8;
    int nsteps = K >> 5;

    f32x4 acc[2][2] = {};

    #pragma unroll
    for (int i = 0; i < 2; i++) {
        stage16(a_src + i * 16 * K, &ab[0][i * 512 + t * 8]);
        stage16(b_src + i * 16 * K, &bb[0][i * 512 + t * 8]);
    }
    __syncthreads();

    for (int s = 0; s < nsteps; s++) {
        int cur = s & 1;
        if (s + 1 < nsteps) {
            int k1 = (s + 1) * 32;
            #pragma unroll
            for (int i = 0; i < 2; i++) {
                stage16(a_src + i * 16 * K + k1, &ab[cur ^ 1][i * 512 + t * 8]);
                stage16(b_src + i * 16 * K + k1, &bb[cur ^ 1][i * 512 + t * 8]);
            }
        }
        f16x8 af[2], bf[2];
        #pragma unroll
        for (int f = 0; f < 2; f++) {
            af[f] = *(const f16x8*)&ab[cur][(f * 16 + rl) * 32 + pu * 8];
            bf[f] = *(const f16x8*)&bb[cur][(f * 16 + rl) * 32 + pu * 8];
        }
        #pragma unroll
        for (int fi = 0; fi < 2; fi++)
            #pragma unroll
            for (int fj = 0; fj < 2; fj++)
                acc[fi][fj] = __builtin_amdgcn_mfma_f32_16x16x32_f16(af[fi], bf[fj], acc[fi][fj], 0, 0, 0);
        __syncthreads();
    }

    #pragma unroll
    for (int fi = 0; fi < 2; fi++)
        #pragma unroll
        for (int fj = 0; fj < 2; fj++) {
            int col = n0 + fj * 16 + rl;
            float bv2 = bias[col];
            #pragma unroll
            for (int r = 0; r < 4; r++) {
                int row = m0 + fi * 16 + kg * 4 + r;
                float v = acc[fi][fj][r] + bv2;
                if (relu) v = fmaxf(v, 0.f);
                out[row * 512 + col] = (f16)v;
            }
        }
}

// ---------------- fused attention: f4 structure, mm from global, fixed swizzle ------
// grid (36 c, 32 b), 512 thr (8 waves), 2 blocks/CU (LDS 66KB). Per BK=32 step: stage
// aw 512x32 (32KB) dbuf via global_load_lds (issued before compute); mm (men frags)
// come DIRECTLY from global — identical addrs across all 8 waves -> L1/L2 broadcast,
// removing the 8x-redundant 512KB/block of LDS mm-reads that made f4 LDS-BW-bound.
// Swizzle (rl>>1)&3 proven conflict-free in R7 (9K vs 4.7M cycles).
__global__ __launch_bounds__(512, 2) void attn_f6(const f16* __restrict__ men,
                                                  const f16* __restrict__ vis,
                                                  const f16* __restrict__ aw1t,
                                                  const float* __restrict__ ab1,
                                                  const float* __restrict__ aw2,
                                                  const float* __restrict__ ab2,
                                                  const float* __restrict__ maskm,
                                                  const float* __restrict__ maskc,
                                                  float* __restrict__ out) {
    __shared__ f16 awb[2][16384];   // [buf][row j 0..511][unit 0..3][8 f16], swizzled
    __shared__ float red[8][64];

    int t = threadIdx.x, lane = t & 63, w = t >> 6;
    int c = blockIdx.x, b = blockIdx.y;
    int rl = lane & 15, kg = lane >> 4;
    int j0 = w * 64;
    int pu = kg ^ ((rl >> 1) & 3);

    int srow = t >> 2;                     // 0..127
    int sk8 = (t & 3) ^ ((srow >> 1) & 3); // (row>>1)&3 == (srow>>1)&3 since 128%8==0
    const f16* aw_src = aw1t + srow * 512 + sk8 * 8;   // + r*128*512 + k0
    const f16* menb = men + (b * 64 + rl) * 512 + kg * 8;
    const f16* visb = vis + (b * 36 + c) * 512;

    f32x4 acc[4][4] = {};

    // prologue: stage step 0 into buf 0
    #pragma unroll
    for (int r = 0; r < 4; r++)
        stage16(aw_src + r * 128 * 512, &awb[0][(r * 512 + t) * 8]);
    __syncthreads();

    for (int s = 0; s < 16; s++) {
        int cur = s & 1;
        if (s < 15) {  // issue next step's staging FIRST; completes under this step's MFMAs
            int k1 = (s + 1) * 32;
            #pragma unroll
            for (int r = 0; r < 4; r++)
                stage16(aw_src + r * 128 * 512 + k1, &awb[cur ^ 1][(r * 512 + t) * 8]);
        }

        f16x8 vv = *(const f16x8*)(visb + s * 32 + kg * 8);
        f16x8 mm[4], bf[4];
        #pragma unroll
        for (int fi = 0; fi < 4; fi++)
            mm[fi] = *(const f16x8*)(menb + fi * 16 * 512 + s * 32);  // global, L1-shared
        #pragma unroll
        for (int fj = 0; fj < 4; fj++)
            bf[fj] = *(const f16x8*)&awb[cur][(j0 + fj * 16 + rl) * 32 + pu * 8];

        #pragma unroll
        for (int fi = 0; fi < 4; fi++) {
            f16x8 a = mm[fi] * vv;   // packed f16 multiply
            #pragma unroll
            for (int fj = 0; fj < 4; fj++)
                acc[fi][fj] = __builtin_amdgcn_mfma_f32_16x16x32_f16(a, bf[fj], acc[fi][fj], 0, 0, 0);
        }
        __syncthreads();  // drains staging vmcnt; protects dbuf swap
    }

    // fp32 epilogue: part[m] = sum over this wave's 64 j of relu(acc + ab1[j]) * aw2[j]
    float ab1v[4], aw2v[4];
    #pragma unroll
    for (int fj = 0; fj < 4; fj++) {
        int j = j0 + fj * 16 + rl;
        ab1v[fj] = ab1[j];
        aw2v[fj] = aw2[j];
    }
    float part[4][4];
    #pragma unroll
    for (int fi = 0; fi < 4; fi++)
        #pragma unroll
        for (int r = 0; r < 4; r++) {
            float s = 0.f;
            #pragma unroll
            for (int fj = 0; fj < 4; fj++)
                s += fmaxf(acc[fi][fj][r] + ab1v[fj], 0.f) * aw2v[fj];
            part[fi][r] = s;
        }
    #pragma unroll
    for (int mask = 1; mask < 16; mask <<= 1)
        #pragma unroll
        for (int fi = 0; fi < 4; fi++)
            #pragma unroll
            for (int r = 0; r < 4; r++)
                part[fi][r] += __shfl_xor(part[fi][r], mask);

    float myv = 0.f;
    #pragma unroll
    for (int fi = 0; fi < 4; fi++)
        #pragma unroll
        for (int r = 0; r < 4; r++)
            myv = (rl == fi * 4 + r) ? part[fi][r] : myv;
    int m = (rl >> 2) * 16 + kg * 4 + (rl & 3);
    red[w][m] = myv;
    __syncthreads();

    if (t < 64) {
        float s = 0.f;
        #pragma unroll
        for (int ww = 0; ww < 8; ww++) s += red[ww][t];
        float v = (s + ab2[0]) * maskm[b * 64 + t] * maskc[b * 36 + c];
        out[(b * 64 + t) * 36 + c] = (v != 0.f) ? v : NEG_INF_F;
    }
}

extern "C" void kernel_launch(void* const* d_in, const int* in_sizes, int n_in,
                              void* d_out, int out_size, void* d_ws, size_t ws_size,
                              hipStream_t stream) {
    const float* ME  = (const float*)d_in[0];   // (32,64,1024)
    const float* CL  = (const float*)d_in[1];   // (32,36,1000)
    const float* MM  = (const float*)d_in[2];   // (32,64)
    const float* CM  = (const float*)d_in[3];   // (32,36)
    const float* VW1 = (const float*)d_in[4];   // (1000,512)
    const float* VB1 = (const float*)d_in[5];
    const float* VW2 = (const float*)d_in[6];   // (512,512)
    const float* VB2 = (const float*)d_in[7];
    const float* MW1 = (const float*)d_in[8];   // (1024,512)
    const float* MB1 = (const float*)d_in[9];
    const float* MW2 = (const float*)d_in[10];  // (512,512)
    const float* MB2 = (const float*)d_in[11];
    const float* AW1 = (const float*)d_in[12];  // (512,512)
    const float* AB1 = (const float*)d_in[13];
    const float* AW2 = (const float*)d_in[14];  // (512,1)
    const float* AB2 = (const float*)d_in[15];  // (1,)
    float* out = (float*)d_out;

    char* ws = (char*)d_ws;
    f16* me_h  = (f16*)ws; ws += (size_t)2048 * 1024 * 2;
    f16* cl_h  = (f16*)ws; ws += (size_t)1152 * 1024 * 2;
    f16* mw1t  = (f16*)ws; ws += (size_t)512 * 1024 * 2;
    f16* vw1t  = (f16*)ws; ws += (size_t)512 * 1024 * 2;
    f16* mw2t  = (f16*)ws; ws += (size_t)512 * 512 * 2;
    f16* vw2t  = (f16*)ws; ws += (size_t)512 * 512 * 2;
    f16* aw1t  = (f16*)ws; ws += (size_t)512 * 512 * 2;
    f16* men1  = (f16*)ws; ws += (size_t)2048 * 512 * 2;
    f16* menh  = (f16*)ws; ws += (size_t)2048 * 512 * 2;
    f16* vis1  = (f16*)ws; ws += (size_t)1152 * 512 * 2;
    f16* vish  = (f16*)ws; ws += (size_t)1152 * 512 * 2;

    prep<<<19968, 256, 0, stream>>>(ME, MW1, VW1, MW2, VW2, AW1, CL,
                                    me_h, mw1t, vw1t, mw2t, vw2t, aw1t, cl_h);
    gemm_stg<<<dim3(100, 16), 64, 0, stream>>>(me_h, cl_h, mw1t, vw1t, MB1, VB1,
                                               men1, vis1, 1024, 1);
    gemm_stg<<<dim3(100, 16), 64, 0, stream>>>(men1, vis1, mw2t, vw2t, MB2, VB2,
                                               menh, vish, 512, 0);
    attn_f6<<<dim3(36, 32), 512, 0, stream>>>(menh, vish, aw1t, AB1, AW2, AB2, MM, CM, out);
}

// Round 14
// 105.490 us; speedup vs baseline: 1.3773x; 1.3773x over previous
//
#include <hip/hip_runtime.h>

typedef _Float16 f16;
typedef _Float16 f16x8 __attribute__((ext_vector_type(8)));
typedef float f32x4 __attribute__((ext_vector_type(4)));

#define NEG_INF_F (-1e10f)

__device__ __forceinline__ void stage16(const f16* g, f16* l) {
    __builtin_amdgcn_global_load_lds((const __attribute__((address_space(1))) void*)g,
                                     (__attribute__((address_space(3))) void*)l, 16, 0, 0);
}

// ---------------- prep: me_h + weight transposes + class_labels pad ----------
__global__ __launch_bounds__(256) void prep(const float* __restrict__ me,
                                            const float* __restrict__ mw1,
                                            const float* __restrict__ vw1,
                                            const float* __restrict__ mw2,
                                            const float* __restrict__ vw2,
                                            const float* __restrict__ aw1,
                                            const float* __restrict__ cl,
                                            f16* __restrict__ me_h,
                                            f16* __restrict__ mw1t, f16* __restrict__ vw1t,
                                            f16* __restrict__ mw2t, f16* __restrict__ vw2t,
                                            f16* __restrict__ aw1t, f16* __restrict__ cl_h) {
    int i = blockIdx.x * 256 + threadIdx.x;
    if (i < 2097152) {
        me_h[i] = (f16)me[i];
        return;
    }
    int j = i - 2097152;
    if (j < 1048576) {
        int seg = j >> 19;
        int jj = j & 524287;
        int k = jj & 1023, n = jj >> 10;
        if (seg == 0) mw1t[n * 1024 + k] = (f16)mw1[k * 512 + n];
        else          vw1t[n * 1024 + k] = (k < 1000) ? (f16)vw1[k * 512 + n] : (f16)0.f;
        return;
    }
    j -= 1048576;
    if (j < 786432) {
        int seg = j >> 18;
        int r = j & 262143;
        int k = r & 511, n = r >> 9;
        const float* src = (seg == 0) ? mw2 : (seg == 1) ? vw2 : aw1;
        f16* dst = (seg == 0) ? mw2t : (seg == 1) ? vw2t : aw1t;
        dst[n * 512 + k] = (f16)src[k * 512 + n];
        return;
    }
    j -= 786432;
    int r = j >> 10, k = j & 1023;
    cl_h[j] = (k < 1000) ? (f16)cl[r * 1000 + k] : (f16)0.f;
}

// ---------------- staged 1-wave GEMM: out = act(A @ Wt^T + bias), 32x32 tile ----------
__global__ __launch_bounds__(64) void gemm_stg(const f16* __restrict__ Am,
                                               const f16* __restrict__ Av,
                                               const f16* __restrict__ Wm,
                                               const f16* __restrict__ Wv,
                                               const float* __restrict__ bm,
                                               const float* __restrict__ bv,
                                               f16* __restrict__ om,
                                               f16* __restrict__ ov,
                                               int K, int relu) {
    __shared__ f16 ab[2][1024], bb[2][1024];  // [buf][row 0..31][unit 0..3][8 f16]

    int t = threadIdx.x;
    int rl = t & 15, kg = t >> 4;
    bool isv = blockIdx.x >= 64;
    int mb = isv ? blockIdx.x - 64 : blockIdx.x;
    const f16* A = isv ? Av : Am;
    const f16* Wt = isv ? Wv : Wm;
    const float* bias = isv ? bv : bm;
    f16* out = isv ? ov : om;
    int m0 = mb * 32, n0 = blockIdx.y * 32;
    int pu = kg ^ ((rl >> 1) & 3);

    int srow = t >> 2;
    int sk8 = (t & 3) ^ ((srow >> 1) & 3);
    const f16* a_src = A + (m0 + srow) * K + sk8 * 8;
    const f16* b_src = Wt + (n0 + srow) * K + sk8 * 8;
    int nsteps = K >> 5;

    f32x4 acc[2][2] = {};

    #pragma unroll
    for (int i = 0; i < 2; i++) {
        stage16(a_src + i * 16 * K, &ab[0][i * 512 + t * 8]);
        stage16(b_src + i * 16 * K, &bb[0][i * 512 + t * 8]);
    }
    __syncthreads();

    for (int s = 0; s < nsteps; s++) {
        int cur = s & 1;
        if (s + 1 < nsteps) {
            int k1 = (s + 1) * 32;
            #pragma unroll
            for (int i = 0; i < 2; i++) {
                stage16(a_src + i * 16 * K + k1, &ab[cur ^ 1][i * 512 + t * 8]);
                stage16(b_src + i * 16 * K + k1, &bb[cur ^ 1][i * 512 + t * 8]);
            }
        }
        f16x8 af[2], bf[2];
        #pragma unroll
        for (int f = 0; f < 2; f++) {
            af[f] = *(const f16x8*)&ab[cur][(f * 16 + rl) * 32 + pu * 8];
            bf[f] = *(const f16x8*)&bb[cur][(f * 16 + rl) * 32 + pu * 8];
        }
        #pragma unroll
        for (int fi = 0; fi < 2; fi++)
            #pragma unroll
            for (int fj = 0; fj < 2; fj++)
                acc[fi][fj] = __builtin_amdgcn_mfma_f32_16x16x32_f16(af[fi], bf[fj], acc[fi][fj], 0, 0, 0);
        __syncthreads();
    }

    #pragma unroll
    for (int fi = 0; fi < 2; fi++)
        #pragma unroll
        for (int fj = 0; fj < 2; fj++) {
            int col = n0 + fj * 16 + rl;
            float bv2 = bias[col];
            #pragma unroll
            for (int r = 0; r < 4; r++) {
                int row = m0 + fi * 16 + kg * 4 + r;
                float v = acc[fi][fj][r] + bv2;
                if (relu) v = fmaxf(v, 0.f);
                out[row * 512 + col] = (f16)v;
            }
        }
}

// ---------------- fused attention f7: 4c per block, all operands LDS ----------------
// grid (9 cq, 2 mh, 32 b) = 576 blocks, 256 thr (4 waves). Block = 4c x 32m x 512j.
// Wave w = j-slot: per pass p (4 passes of 128 j), wave covers j = p*128 + w*32.
// Per BK=32 step: stage aw 128x32 (8KB) + men 32x32 (2KB) dbuf; vis staged ONCE (4KB);
// wave reads mm[2]+bf[2] (4 swizzled ds_read_b128) + vv[4] (LDS broadcast) -> 16 MFMAs.
// ZERO global loads in the K loop (R8 lesson: any inline global load is fatal).
// Pass-end folds accumulate into red[] in LDS (saves psum registers).
__global__ __launch_bounds__(256, 3) void attn_f7(const f16* __restrict__ men,
                                                  const f16* __restrict__ vis,
                                                  const f16* __restrict__ aw1t,
                                                  const float* __restrict__ ab1,
                                                  const float* __restrict__ aw2,
                                                  const float* __restrict__ ab2,
                                                  const float* __restrict__ maskm,
                                                  const float* __restrict__ maskc,
                                                  float* __restrict__ out) {
    __shared__ f16 awb[2][4096];    // [buf][row 0..127][unit 0..3][8 f16], swizzled
    __shared__ f16 mnb[2][1024];    // [buf][row 0..31][unit][8], swizzled
    __shared__ f16 vist[2048];      // [c 0..3][k 0..511], staged once
    __shared__ float red[4][4][32]; // [jq][c][m]

    int t = threadIdx.x, lane = t & 63, w = t >> 6;   // w = jq
    int cq = blockIdx.x, mhb = blockIdx.y, b = blockIdx.z;
    int c0 = cq * 4;
    int rl = lane & 15, kg = lane >> 4;
    int pu = kg ^ ((rl >> 1) & 3);

    // staging addresses (pre-swizzled global source, linear LDS dest = G21)
    int srow = t >> 2;                       // 0..63
    int sk8 = (t & 3) ^ ((srow >> 1) & 3);   // valid for srow and srow+64 (64%8==0... (row>>1)&3 shifts by 32 ≡ 0 mod 4)
    const f16* aw_src = aw1t + srow * 512 + sk8 * 8;                       // + (p*128+i*64)*512 + k
    const f16* mn_src = men + (b * 64 + mhb * 32 + srow) * 512 + sk8 * 8;  // t<128 only
    const f16* vi_src = vis + (b * 36 + c0 + (t >> 6)) * 512 + (t & 63) * 8;

    // zero red
    ((float*)red)[t] = 0.f;
    ((float*)red)[256 + t] = 0.f;

    f32x4 acc[4][2][2] = {};   // [c][fi][fj]

    // prologue: stage vis (once) + pass0/step0 into buf 0
    stage16(vi_src, &vist[t * 8]);
    #pragma unroll
    for (int i = 0; i < 2; i++)
        stage16(aw_src + i * 64 * 512, &awb[0][(i * 256 + t) * 8]);
    if (t < 128)
        stage16(mn_src, &mnb[0][t * 8]);
    __syncthreads();

    for (int ss = 0; ss < 64; ss++) {
        int p = ss >> 4, s = ss & 15, cur = ss & 1;
        if (ss < 63) {  // issue next step's staging FIRST
            int pn = (ss + 1) >> 4, sn = (ss + 1) & 15;
            #pragma unroll
            for (int i = 0; i < 2; i++)
                stage16(aw_src + (pn * 128 + i * 64) * 512 + sn * 32,
                        &awb[cur ^ 1][(i * 256 + t) * 8]);
            if (t < 128)
                stage16(mn_src + sn * 32, &mnb[cur ^ 1][t * 8]);
        }

        f16x8 mm[2], bf[2], vv[4];
        #pragma unroll
        for (int f = 0; f < 2; f++) {
            mm[f] = *(const f16x8*)&mnb[cur][((f * 16 + rl) * 4 + pu) * 8];
            bf[f] = *(const f16x8*)&awb[cur][((w * 32 + f * 16 + rl) * 4 + pu) * 8];
        }
        #pragma unroll
        for (int c = 0; c < 4; c++)
            vv[c] = *(const f16x8*)&vist[c * 512 + s * 32 + kg * 8];  // broadcast, conflict-free

        #pragma unroll
        for (int fi = 0; fi < 2; fi++)
            #pragma unroll
            for (int c = 0; c < 4; c++) {
                f16x8 a = mm[fi] * vv[c];   // packed f16 multiply
                #pragma unroll
                for (int fj = 0; fj < 2; fj++)
                    acc[c][fi][fj] = __builtin_amdgcn_mfma_f32_16x16x32_f16(a, bf[fj], acc[c][fi][fj], 0, 0, 0);
            }
        __syncthreads();

        if (s == 15) {  // end of pass p: fold acc into red, reset acc
            int j0 = p * 128 + w * 32;
            float ab1v[2], aw2v[2];
            #pragma unroll
            for (int fj = 0; fj < 2; fj++) {
                int j = j0 + fj * 16 + rl;
                ab1v[fj] = ab1[j];
                aw2v[fj] = aw2[j];
            }
            #pragma unroll
            for (int c = 0; c < 4; c++) {
                float part[2][4];
                #pragma unroll
                for (int fi = 0; fi < 2; fi++)
                    #pragma unroll
                    for (int r = 0; r < 4; r++) {
                        float sv = 0.f;
                        #pragma unroll
                        for (int fj = 0; fj < 2; fj++)
                            sv += fmaxf(acc[c][fi][fj][r] + ab1v[fj], 0.f) * aw2v[fj];
                        part[fi][r] = sv;
                    }
                #pragma unroll
                for (int mask = 1; mask < 16; mask <<= 1)
                    #pragma unroll
                    for (int fi = 0; fi < 2; fi++)
                        #pragma unroll
                        for (int r = 0; r < 4; r++)
                            part[fi][r] += __shfl_xor(part[fi][r], mask);
                float myv = 0.f;
                #pragma unroll
                for (int fi = 0; fi < 2; fi++)
                    #pragma unroll
                    for (int r = 0; r < 4; r++)
                        myv = (rl == fi * 4 + r) ? part[fi][r] : myv;
                if (rl < 8) {
                    int m = (rl >> 2) * 16 + kg * 4 + (rl & 3);
                    red[w][c][m] += myv;
                }
            }
            #pragma unroll
            for (int c = 0; c < 4; c++)
                #pragma unroll
                for (int fi = 0; fi < 2; fi++)
                    #pragma unroll
                    for (int fj = 0; fj < 2; fj++)
                        acc[c][fi][fj] = (f32x4){0.f, 0.f, 0.f, 0.f};
        }
    }
    __syncthreads();

    if (t < 128) {
        int ci = t >> 5, m = t & 31;
        float s = red[0][ci][m] + red[1][ci][m] + red[2][ci][m] + red[3][ci][m];
        int c = c0 + ci;
        int gm = mhb * 32 + m;
        float v = (s + ab2[0]) * maskm[b * 64 + gm] * maskc[b * 36 + c];
        out[(b * 64 + gm) * 36 + c] = (v != 0.f) ? v : NEG_INF_F;
    }
}

extern "C" void kernel_launch(void* const* d_in, const int* in_sizes, int n_in,
                              void* d_out, int out_size, void* d_ws, size_t ws_size,
                              hipStream_t stream) {
    const float* ME  = (const float*)d_in[0];   // (32,64,1024)
    const float* CL  = (const float*)d_in[1];   // (32,36,1000)
    const float* MM  = (const float*)d_in[2];   // (32,64)
    const float* CM  = (const float*)d_in[3];   // (32,36)
    const float* VW1 = (const float*)d_in[4];   // (1000,512)
    const float* VB1 = (const float*)d_in[5];
    const float* VW2 = (const float*)d_in[6];   // (512,512)
    const float* VB2 = (const float*)d_in[7];
    const float* MW1 = (const float*)d_in[8];   // (1024,512)
    const float* MB1 = (const float*)d_in[9];
    const float* MW2 = (const float*)d_in[10];  // (512,512)
    const float* MB2 = (const float*)d_in[11];
    const float* AW1 = (const float*)d_in[12];  // (512,512)
    const float* AB1 = (const float*)d_in[13];
    const float* AW2 = (const float*)d_in[14];  // (512,1)
    const float* AB2 = (const float*)d_in[15];  // (1,)
    float* out = (float*)d_out;

    char* ws = (char*)d_ws;
    f16* me_h  = (f16*)ws; ws += (size_t)2048 * 1024 * 2;
    f16* cl_h  = (f16*)ws; ws += (size_t)1152 * 1024 * 2;
    f16* mw1t  = (f16*)ws; ws += (size_t)512 * 1024 * 2;
    f16* vw1t  = (f16*)ws; ws += (size_t)512 * 1024 * 2;
    f16* mw2t  = (f16*)ws; ws += (size_t)512 * 512 * 2;
    f16* vw2t  = (f16*)ws; ws += (size_t)512 * 512 * 2;
    f16* aw1t  = (f16*)ws; ws += (size_t)512 * 512 * 2;
    f16* men1  = (f16*)ws; ws += (size_t)2048 * 512 * 2;
    f16* menh  = (f16*)ws; ws += (size_t)2048 * 512 * 2;
    f16* vis1  = (f16*)ws; ws += (size_t)1152 * 512 * 2;
    f16* vish  = (f16*)ws; ws += (size_t)1152 * 512 * 2;

    prep<<<19968, 256, 0, stream>>>(ME, MW1, VW1, MW2, VW2, AW1, CL,
                                    me_h, mw1t, vw1t, mw2t, vw2t, aw1t, cl_h);
    gemm_stg<<<dim3(100, 16), 64, 0, stream>>>(me_h, cl_h, mw1t, vw1t, MB1, VB1,
                                               men1, vis1, 1024, 1);
    gemm_stg<<<dim3(100, 16), 64, 0, stream>>>(men1, vis1, mw2t, vw2t, MB2, VB2,
                                               menh, vish, 512, 0);
    attn_f7<<<dim3(9, 2, 32), 256, 0, stream>>>(menh, vish, aw1t, AB1, AW2, AB2, MM, CM, out);
}

// Round 15
// 97.912 us; speedup vs baseline: 1.4839x; 1.0774x over previous
//
#include <hip/hip_runtime.h>

typedef _Float16 f16;
typedef _Float16 f16x8 __attribute__((ext_vector_type(8)));
typedef float f32x4 __attribute__((ext_vector_type(4)));

#define NEG_INF_F (-1e10f)

__device__ __forceinline__ void stage16(const f16* g, f16* l) {
    __builtin_amdgcn_global_load_lds((const __attribute__((address_space(1))) void*)g,
                                     (__attribute__((address_space(3))) void*)l, 16, 0, 0);
}

// ---------------- prep: me_h + weight transposes + class_labels pad ----------
__global__ __launch_bounds__(256) void prep(const float* __restrict__ me,
                                            const float* __restrict__ mw1,
                                            const float* __restrict__ vw1,
                                            const float* __restrict__ mw2,
                                            const float* __restrict__ vw2,
                                            const float* __restrict__ aw1,
                                            const float* __restrict__ cl,
                                            f16* __restrict__ me_h,
                                            f16* __restrict__ mw1t, f16* __restrict__ vw1t,
                                            f16* __restrict__ mw2t, f16* __restrict__ vw2t,
                                            f16* __restrict__ aw1t, f16* __restrict__ cl_h) {
    int i = blockIdx.x * 256 + threadIdx.x;
    if (i < 2097152) {
        me_h[i] = (f16)me[i];
        return;
    }
    int j = i - 2097152;
    if (j < 1048576) {
        int seg = j >> 19;
        int jj = j & 524287;
        int k = jj & 1023, n = jj >> 10;
        if (seg == 0) mw1t[n * 1024 + k] = (f16)mw1[k * 512 + n];
        else          vw1t[n * 1024 + k] = (k < 1000) ? (f16)vw1[k * 512 + n] : (f16)0.f;
        return;
    }
    j -= 1048576;
    if (j < 786432) {
        int seg = j >> 18;
        int r = j & 262143;
        int k = r & 511, n = r >> 9;
        const float* src = (seg == 0) ? mw2 : (seg == 1) ? vw2 : aw1;
        f16* dst = (seg == 0) ? mw2t : (seg == 1) ? vw2t : aw1t;
        dst[n * 512 + k] = (f16)src[k * 512 + n];
        return;
    }
    j -= 786432;
    int r = j >> 10, k = j & 1023;
    cl_h[j] = (k < 1000) ? (f16)cl[r * 1000 + k] : (f16)0.f;
}

// ---------------- staged 1-wave GEMM: out = act(A @ Wt^T + bias), 32x32 tile ----------
__global__ __launch_bounds__(64) void gemm_stg(const f16* __restrict__ Am,
                                               const f16* __restrict__ Av,
                                               const f16* __restrict__ Wm,
                                               const f16* __restrict__ Wv,
                                               const float* __restrict__ bm,
                                               const float* __restrict__ bv,
                                               f16* __restrict__ om,
                                               f16* __restrict__ ov,
                                               int K, int relu) {
    __shared__ f16 ab[2][1024], bb[2][1024];  // [buf][row 0..31][unit 0..3][8 f16]

    int t = threadIdx.x;
    int rl = t & 15, kg = t >> 4;
    bool isv = blockIdx.x >= 64;
    int mb = isv ? blockIdx.x - 64 : blockIdx.x;
    const f16* A = isv ? Av : Am;
    const f16* Wt = isv ? Wv : Wm;
    const float* bias = isv ? bv : bm;
    f16* out = isv ? ov : om;
    int m0 = mb * 32, n0 = blockIdx.y * 32;
    int pu = kg ^ ((rl >> 1) & 3);

    int srow = t >> 2;
    int sk8 = (t & 3) ^ ((srow >> 1) & 3);
    const f16* a_src = A + (m0 + srow) * K + sk8 * 8;
    const f16* b_src = Wt + (n0 + srow) * K + sk8 * 8;
    int nsteps = K >> 5;

    f32x4 acc[2][2] = {};

    #pragma unroll
    for (int i = 0; i < 2; i++) {
        stage16(a_src + i * 16 * K, &ab[0][i * 512 + t * 8]);
        stage16(b_src + i * 16 * K, &bb[0][i * 512 + t * 8]);
    }
    __syncthreads();

    for (int s = 0; s < nsteps; s++) {
        int cur = s & 1;
        if (s + 1 < nsteps) {
            int k1 = (s + 1) * 32;
            #pragma unroll
            for (int i = 0; i < 2; i++) {
                stage16(a_src + i * 16 * K + k1, &ab[cur ^ 1][i * 512 + t * 8]);
                stage16(b_src + i * 16 * K + k1, &bb[cur ^ 1][i * 512 + t * 8]);
            }
        }
        f16x8 af[2], bf[2];
        #pragma unroll
        for (int f = 0; f < 2; f++) {
            af[f] = *(const f16x8*)&ab[cur][(f * 16 + rl) * 32 + pu * 8];
            bf[f] = *(const f16x8*)&bb[cur][(f * 16 + rl) * 32 + pu * 8];
        }
        #pragma unroll
        for (int fi = 0; fi < 2; fi++)
            #pragma unroll
            for (int fj = 0; fj < 2; fj++)
                acc[fi][fj] = __builtin_amdgcn_mfma_f32_16x16x32_f16(af[fi], bf[fj], acc[fi][fj], 0, 0, 0);
        __syncthreads();
    }

    #pragma unroll
    for (int fi = 0; fi < 2; fi++)
        #pragma unroll
        for (int fj = 0; fj < 2; fj++) {
            int col = n0 + fj * 16 + rl;
            float bv2 = bias[col];
            #pragma unroll
            for (int r = 0; r < 4; r++) {
                int row = m0 + fi * 16 + kg * 4 + r;
                float v = acc[fi][fj][r] + bv2;
                if (relu) v = fmaxf(v, 0.f);
                out[row * 512 + col] = (f16)v;
            }
        }
}

// ---------------- fused attention f8: f7 step structure, 4x blocks, j-split ----------
// grid (9 cq, 8 = mh + 4 jh, 32 b) = 2304 blocks, 256 thr (4 waves), bounds(256,4).
// Block = 4c x 32m x 128j x K=512, ONE pass of 16 BK=32 steps. Wave w owns j-slot
// w*32 within the block's 128 j. Zero global loads in K loop; all operands staged
// (aw 8KB + men 2KB dbuf, vis 4KB once). Partial sums -> scratch; postproc combines.
__global__ __launch_bounds__(256, 4) void attn_f8(const f16* __restrict__ men,
                                                  const f16* __restrict__ vis,
                                                  const f16* __restrict__ aw1t,
                                                  const float* __restrict__ ab1,
                                                  const float* __restrict__ aw2,
                                                  float* __restrict__ partial) {
    __shared__ f16 awb[2][4096];    // [buf][row 0..127][unit 0..3][8 f16], swizzled
    __shared__ f16 mnb[2][1024];    // [buf][row 0..31][unit][8], swizzled
    __shared__ f16 vist[2048];      // [c 0..3][k 0..511], staged once
    __shared__ float red[4][4][32]; // [wave][c][m]

    int t = threadIdx.x, lane = t & 63, w = t >> 6;
    int cq = blockIdx.x, sl = blockIdx.y, b = blockIdx.z;
    int mhb = sl & 1, jh = sl >> 1;
    int c0 = cq * 4;
    int rl = lane & 15, kg = lane >> 4;
    int pu = kg ^ ((rl >> 1) & 3);

    int srow = t >> 2;                       // 0..63
    int sk8 = (t & 3) ^ ((srow >> 1) & 3);
    const f16* aw_src = aw1t + (jh * 128 + srow) * 512 + sk8 * 8;          // + i*64*512 + k
    const f16* mn_src = men + (b * 64 + mhb * 32 + srow) * 512 + sk8 * 8;  // t<128 only
    const f16* vi_src = vis + (b * 36 + c0 + (t >> 6)) * 512 + (t & 63) * 8;

    f32x4 acc[4][2][2] = {};   // [c][fi][fj]

    // prologue: stage vis (once) + step0 into buf 0
    stage16(vi_src, &vist[t * 8]);
    #pragma unroll
    for (int i = 0; i < 2; i++)
        stage16(aw_src + i * 64 * 512, &awb[0][(i * 256 + t) * 8]);
    if (t < 128)
        stage16(mn_src, &mnb[0][t * 8]);
    __syncthreads();

    for (int s = 0; s < 16; s++) {
        int cur = s & 1;
        if (s < 15) {  // issue next step's staging FIRST
            int k1 = (s + 1) * 32;
            #pragma unroll
            for (int i = 0; i < 2; i++)
                stage16(aw_src + i * 64 * 512 + k1, &awb[cur ^ 1][(i * 256 + t) * 8]);
            if (t < 128)
                stage16(mn_src + k1, &mnb[cur ^ 1][t * 8]);
        }

        f16x8 mm[2], bf[2], vv[4];
        #pragma unroll
        for (int f = 0; f < 2; f++) {
            mm[f] = *(const f16x8*)&mnb[cur][((f * 16 + rl) * 4 + pu) * 8];
            bf[f] = *(const f16x8*)&awb[cur][((w * 32 + f * 16 + rl) * 4 + pu) * 8];
        }
        #pragma unroll
        for (int c = 0; c < 4; c++)
            vv[c] = *(const f16x8*)&vist[c * 512 + s * 32 + kg * 8];  // broadcast

        #pragma unroll
        for (int fi = 0; fi < 2; fi++)
            #pragma unroll
            for (int c = 0; c < 4; c++) {
                f16x8 a = mm[fi] * vv[c];   // packed f16 multiply
                #pragma unroll
                for (int fj = 0; fj < 2; fj++)
                    acc[c][fi][fj] = __builtin_amdgcn_mfma_f32_16x16x32_f16(a, bf[fj], acc[c][fi][fj], 0, 0, 0);
            }
        __syncthreads();
    }

    // fold: part[m] = sum over this wave's 32 j of relu(acc + ab1) * aw2 (fp32)
    int j0 = jh * 128 + w * 32;
    float ab1v[2], aw2v[2];
    #pragma unroll
    for (int fj = 0; fj < 2; fj++) {
        int j = j0 + fj * 16 + rl;
        ab1v[fj] = ab1[j];
        aw2v[fj] = aw2[j];
    }
    #pragma unroll
    for (int c = 0; c < 4; c++) {
        float part[2][4];
        #pragma unroll
        for (int fi = 0; fi < 2; fi++)
            #pragma unroll
            for (int r = 0; r < 4; r++) {
                float sv = 0.f;
                #pragma unroll
                for (int fj = 0; fj < 2; fj++)
                    sv += fmaxf(acc[c][fi][fj][r] + ab1v[fj], 0.f) * aw2v[fj];
                part[fi][r] = sv;
            }
        #pragma unroll
        for (int mask = 1; mask < 16; mask <<= 1)
            #pragma unroll
            for (int fi = 0; fi < 2; fi++)
                #pragma unroll
                for (int r = 0; r < 4; r++)
                    part[fi][r] += __shfl_xor(part[fi][r], mask);
        float myv = 0.f;
        #pragma unroll
        for (int fi = 0; fi < 2; fi++)
            #pragma unroll
            for (int r = 0; r < 4; r++)
                myv = (rl == fi * 4 + r) ? part[fi][r] : myv;
        if (rl < 8) {
            int m = (rl >> 2) * 16 + kg * 4 + (rl & 3);
            red[w][c][m] = myv;
        }
    }
    __syncthreads();

    if (t < 128) {
        int ci = t >> 5, m = t & 31;
        float s = red[0][ci][m] + red[1][ci][m] + red[2][ci][m] + red[3][ci][m];
        int gm = mhb * 32 + m;
        partial[((jh * 32 + b) * 64 + gm) * 36 + c0 + ci] = s;
    }
}

// ---------------- post-process: sum 4 jh partials, + ab2, masks, NEG_INF ------------
__global__ __launch_bounds__(256) void postproc(const float* __restrict__ partial,
                                                const float* __restrict__ mm,
                                                const float* __restrict__ cm,
                                                const float* __restrict__ ab2,
                                                float* __restrict__ out) {
    int i = blockIdx.x * 256 + threadIdx.x;  // < 73728
    int b = i / 2304;
    int rest = i - b * 2304;
    int m = rest / 36, c = rest - m * 36;
    float s = 0.f;
    #pragma unroll
    for (int jh = 0; jh < 4; jh++)
        s += partial[((jh * 32 + b) * 64 + m) * 36 + c];
    float v = (s + ab2[0]) * mm[b * 64 + m] * cm[b * 36 + c];
    out[i] = (v != 0.f) ? v : NEG_INF_F;
}

extern "C" void kernel_launch(void* const* d_in, const int* in_sizes, int n_in,
                              void* d_out, int out_size, void* d_ws, size_t ws_size,
                              hipStream_t stream) {
    const float* ME  = (const float*)d_in[0];   // (32,64,1024)
    const float* CL  = (const float*)d_in[1];   // (32,36,1000)
    const float* MM  = (const float*)d_in[2];   // (32,64)
    const float* CM  = (const float*)d_in[3];   // (32,36)
    const float* VW1 = (const float*)d_in[4];   // (1000,512)
    const float* VB1 = (const float*)d_in[5];
    const float* VW2 = (const float*)d_in[6];   // (512,512)
    const float* VB2 = (const float*)d_in[7];
    const float* MW1 = (const float*)d_in[8];   // (1024,512)
    const float* MB1 = (const float*)d_in[9];
    const float* MW2 = (const float*)d_in[10];  // (512,512)
    const float* MB2 = (const float*)d_in[11];
    const float* AW1 = (const float*)d_in[12];  // (512,512)
    const float* AB1 = (const float*)d_in[13];
    const float* AW2 = (const float*)d_in[14];  // (512,1)
    const float* AB2 = (const float*)d_in[15];  // (1,)
    float* out = (float*)d_out;

    char* ws = (char*)d_ws;
    f16* me_h  = (f16*)ws; ws += (size_t)2048 * 1024 * 2;
    f16* cl_h  = (f16*)ws; ws += (size_t)1152 * 1024 * 2;
    f16* mw1t  = (f16*)ws; ws += (size_t)512 * 1024 * 2;
    f16* vw1t  = (f16*)ws; ws += (size_t)512 * 1024 * 2;
    f16* mw2t  = (f16*)ws; ws += (size_t)512 * 512 * 2;
    f16* vw2t  = (f16*)ws; ws += (size_t)512 * 512 * 2;
    f16* aw1t  = (f16*)ws; ws += (size_t)512 * 512 * 2;
    f16* men1  = (f16*)ws; ws += (size_t)2048 * 512 * 2;
    f16* menh  = (f16*)ws; ws += (size_t)2048 * 512 * 2;
    f16* vis1  = (f16*)ws; ws += (size_t)1152 * 512 * 2;
    f16* vish  = (f16*)ws; ws += (size_t)1152 * 512 * 2;
    float* part = (float*)ws; ws += (size_t)4 * 32 * 64 * 36 * 4;

    prep<<<19968, 256, 0, stream>>>(ME, MW1, VW1, MW2, VW2, AW1, CL,
                                    me_h, mw1t, vw1t, mw2t, vw2t, aw1t, cl_h);
    gemm_stg<<<dim3(100, 16), 64, 0, stream>>>(me_h, cl_h, mw1t, vw1t, MB1, VB1,
                                               men1, vis1, 1024, 1);
    gemm_stg<<<dim3(100, 16), 64, 0, stream>>>(men1, vis1, mw2t, vw2t, MB2, VB2,
                                               menh, vish, 512, 0);
    attn_f8<<<dim3(9, 8, 32), 256, 0, stream>>>(menh, vish, aw1t, AB1, AW2, part);
    postproc<<<288, 256, 0, stream>>>(part, MM, CM, AB2, out);
}

// Round 16
// 95.142 us; speedup vs baseline: 1.5271x; 1.0291x over previous
//
#include <hip/hip_runtime.h>

typedef _Float16 f16;
typedef _Float16 f16x8 __attribute__((ext_vector_type(8)));
typedef _Float16 f16x4 __attribute__((ext_vector_type(4)));
typedef float f32x4 __attribute__((ext_vector_type(4)));
typedef float fl4 __attribute__((ext_vector_type(4)));

#define NEG_INF_F (-1e10f)

__device__ __forceinline__ void stage16(const f16* g, f16* l) {
    __builtin_amdgcn_global_load_lds((const __attribute__((address_space(1))) void*)g,
                                     (__attribute__((address_space(3))) void*)l, 16, 0, 0);
}

// ---------------- prep2: tiled transposes (both sides coalesced) + conversions -------
// bx < 1792: 32x32 LDS-tile transpose of the 5 weight mats (f32 KxN -> f16 NxKp)
// bx < 3840: me_h float4 convert;  bx < 4992: cl_h pad convert (row stride 1000->1024)
__global__ __launch_bounds__(256) void prep2(const float* __restrict__ me,
                                             const float* __restrict__ mw1,
                                             const float* __restrict__ vw1,
                                             const float* __restrict__ mw2,
                                             const float* __restrict__ vw2,
                                             const float* __restrict__ aw1,
                                             const float* __restrict__ cl,
                                             f16* __restrict__ me_h,
                                             f16* __restrict__ mw1t, f16* __restrict__ vw1t,
                                             f16* __restrict__ mw2t, f16* __restrict__ vw2t,
                                             f16* __restrict__ aw1t, f16* __restrict__ cl_h) {
    int bx = blockIdx.x, t = threadIdx.x;
    if (bx < 1792) {
        __shared__ float tile[32][33];
        const float* src; f16* dst; int Ksrc, Kp, tid;
        if (bx < 512)       { src = mw1; dst = mw1t; Ksrc = 1024; Kp = 1024; tid = bx; }
        else if (bx < 1024) { src = vw1; dst = vw1t; Ksrc = 1000; Kp = 1024; tid = bx - 512; }
        else if (bx < 1280) { src = mw2; dst = mw2t; Ksrc = 512;  Kp = 512;  tid = bx - 1024; }
        else if (bx < 1536) { src = vw2; dst = vw2t; Ksrc = 512;  Kp = 512;  tid = bx - 1280; }
        else                { src = aw1; dst = aw1t; Ksrc = 512;  Kp = 512;  tid = bx - 1536; }
        int tk = tid >> 4, tn = tid & 15;          // n-dim always 512 -> 16 tiles
        int x = t & 31, y = t >> 5;                // 32 x 8
        #pragma unroll
        for (int r = 0; r < 4; r++) {
            int k = tk * 32 + y * 4 + r;
            tile[y * 4 + r][x] = (k < Ksrc) ? src[k * 512 + tn * 32 + x] : 0.f;
        }
        __syncthreads();
        #pragma unroll
        for (int r = 0; r < 4; r++) {
            int n = tn * 32 + y * 4 + r;
            dst[n * Kp + tk * 32 + x] = (f16)tile[x][y * 4 + r];
        }
        return;
    }
    if (bx < 3840) {
        int i = (bx - 1792) * 256 + t;
        fl4 v = *(const fl4*)(me + i * 4);
        f16x4 h;
        #pragma unroll
        for (int e = 0; e < 4; e++) h[e] = (f16)v[e];
        *(f16x4*)(me_h + i * 4) = h;
        return;
    }
    {
        int i = (bx - 3840) * 256 + t;
        int idx = i * 4;
        int r = idx >> 10, k0 = idx & 1023;
        f16x4 h;
        if (k0 < 1000) {
            fl4 v = *(const fl4*)(cl + r * 1000 + k0);
            #pragma unroll
            for (int e = 0; e < 4; e++) h[e] = (f16)v[e];
        } else {
            #pragma unroll
            for (int e = 0; e < 4; e++) h[e] = (f16)0.f;
        }
        *(f16x4*)(cl_h + idx) = h;
    }
}

// ---------------- staged 1-wave GEMM: out = act(A @ Wt^T + bias), 32x32 tile ----------
__global__ __launch_bounds__(64) void gemm_stg(const f16* __restrict__ Am,
                                               const f16* __restrict__ Av,
                                               const f16* __restrict__ Wm,
                                               const f16* __restrict__ Wv,
                                               const float* __restrict__ bm,
                                               const float* __restrict__ bv,
                                               f16* __restrict__ om,
                                               f16* __restrict__ ov,
                                               int K, int relu) {
    __shared__ f16 ab[2][1024], bb[2][1024];  // [buf][row 0..31][unit 0..3][8 f16]

    int t = threadIdx.x;
    int rl = t & 15, kg = t >> 4;
    bool isv = blockIdx.x >= 64;
    int mb = isv ? blockIdx.x - 64 : blockIdx.x;
    const f16* A = isv ? Av : Am;
    const f16* Wt = isv ? Wv : Wm;
    const float* bias = isv ? bv : bm;
    f16* out = isv ? ov : om;
    int m0 = mb * 32, n0 = blockIdx.y * 32;
    int pu = kg ^ ((rl >> 1) & 3);

    int srow = t >> 2;
    int sk8 = (t & 3) ^ ((srow >> 1) & 3);
    const f16* a_src = A + (m0 + srow) * K + sk8 * 8;
    const f16* b_src = Wt + (n0 + srow) * K + sk8 * 8;
    int nsteps = K >> 5;

    f32x4 acc[2][2] = {};

    #pragma unroll
    for (int i = 0; i < 2; i++) {
        stage16(a_src + i * 16 * K, &ab[0][i * 512 + t * 8]);
        stage16(b_src + i * 16 * K, &bb[0][i * 512 + t * 8]);
    }
    __syncthreads();

    for (int s = 0; s < nsteps; s++) {
        int cur = s & 1;
        if (s + 1 < nsteps) {
            int k1 = (s + 1) * 32;
            #pragma unroll
            for (int i = 0; i < 2; i++) {
                stage16(a_src + i * 16 * K + k1, &ab[cur ^ 1][i * 512 + t * 8]);
                stage16(b_src + i * 16 * K + k1, &bb[cur ^ 1][i * 512 + t * 8]);
            }
        }
        f16x8 af[2], bf[2];
        #pragma unroll
        for (int f = 0; f < 2; f++) {
            af[f] = *(const f16x8*)&ab[cur][(f * 16 + rl) * 32 + pu * 8];
            bf[f] = *(const f16x8*)&bb[cur][(f * 16 + rl) * 32 + pu * 8];
        }
        #pragma unroll
        for (int fi = 0; fi < 2; fi++)
            #pragma unroll
            for (int fj = 0; fj < 2; fj++)
                acc[fi][fj] = __builtin_amdgcn_mfma_f32_16x16x32_f16(af[fi], bf[fj], acc[fi][fj], 0, 0, 0);
        __syncthreads();
    }

    #pragma unroll
    for (int fi = 0; fi < 2; fi++)
        #pragma unroll
        for (int fj = 0; fj < 2; fj++) {
            int col = n0 + fj * 16 + rl;
            float bv2 = bias[col];
            #pragma unroll
            for (int r = 0; r < 4; r++) {
                int row = m0 + fi * 16 + kg * 4 + r;
                float v = acc[fi][fj][r] + bv2;
                if (relu) v = fmaxf(v, 0.f);
                out[row * 512 + col] = (f16)v;
            }
        }
}

// ---------------- fused attention f9: wave = 32m x 64j x 2c (1 pk_mul per MFMA) -----
// grid (18 cp, 4 = mh + 2 jh, 32 b) = 2304 blocks, 256 thr (4 waves), bounds(256,4).
// Block = 2c x 32m x 256j x K=512, one pass of 16 BK=32 steps; wave w owns j-slot w*64.
// Per step: stage aw 256x32 (16KB) + men 32x32 (2KB) dbuf; vis 2c staged once (2KB);
// reads mm[2]+bf[4] (6 swizzled ds_read_b128) + vv[2] broadcast -> 4 builds, 16 MFMAs.
// Zero global loads in K loop. Partials -> scratch; postproc combines 2 jh.
__global__ __launch_bounds__(256, 4) void attn_f9(const f16* __restrict__ men,
                                                  const f16* __restrict__ vis,
                                                  const f16* __restrict__ aw1t,
                                                  const float* __restrict__ ab1,
                                                  const float* __restrict__ aw2,
                                                  float* __restrict__ partial) {
    __shared__ f16 awb[2][8192];    // [buf][row 0..255][unit 0..3][8 f16], swizzled
    __shared__ f16 mnb[2][1024];    // [buf][row 0..31][unit][8], swizzled
    __shared__ f16 vist[1024];      // [c 0..1][k 0..511], staged once
    __shared__ float red[4][2][32]; // [wave][c][m]

    int t = threadIdx.x, lane = t & 63, w = t >> 6;
    int cp = blockIdx.x, sl = blockIdx.y, b = blockIdx.z;
    int mhb = sl & 1, jh = sl >> 1;
    int c0 = cp * 2;
    int rl = lane & 15, kg = lane >> 4;
    int pu = kg ^ ((rl >> 1) & 3);

    int srow = t >> 2;                       // 0..63
    int sk8 = (t & 3) ^ ((srow >> 1) & 3);
    const f16* aw_src = aw1t + (jh * 256 + srow) * 512 + sk8 * 8;          // + i*64*512 + k
    const f16* mn_src = men + (b * 64 + mhb * 32 + srow) * 512 + sk8 * 8;  // t<128 only
    const f16* vi_src = vis + (b * 36 + c0 + (t >> 6)) * 512 + (t & 63) * 8;  // t<128

    f32x4 acc[2][2][4] = {};   // [c][fi][fj]

    // prologue: stage vis (once) + step0 into buf 0
    if (t < 128) {
        stage16(vi_src, &vist[t * 8]);
        stage16(mn_src, &mnb[0][t * 8]);
    }
    #pragma unroll
    for (int i = 0; i < 4; i++)
        stage16(aw_src + i * 64 * 512, &awb[0][(i * 256 + t) * 8]);
    __syncthreads();

    for (int s = 0; s < 16; s++) {
        int cur = s & 1;
        if (s < 15) {  // issue next step's staging FIRST
            int k1 = (s + 1) * 32;
            #pragma unroll
            for (int i = 0; i < 4; i++)
                stage16(aw_src + i * 64 * 512 + k1, &awb[cur ^ 1][(i * 256 + t) * 8]);
            if (t < 128)
                stage16(mn_src + k1, &mnb[cur ^ 1][t * 8]);
        }

        f16x8 mm[2], bf[4], vv[2];
        #pragma unroll
        for (int f = 0; f < 2; f++)
            mm[f] = *(const f16x8*)&mnb[cur][((f * 16 + rl) * 4 + pu) * 8];
        #pragma unroll
        for (int fj = 0; fj < 4; fj++)
            bf[fj] = *(const f16x8*)&awb[cur][((w * 64 + fj * 16 + rl) * 4 + pu) * 8];
        #pragma unroll
        for (int c = 0; c < 2; c++)
            vv[c] = *(const f16x8*)&vist[c * 512 + s * 32 + kg * 8];  // broadcast

        #pragma unroll
        for (int fi = 0; fi < 2; fi++)
            #pragma unroll
            for (int c = 0; c < 2; c++) {
                f16x8 a = mm[fi] * vv[c];   // 4 pk_mul -> feeds 4 MFMAs
                #pragma unroll
                for (int fj = 0; fj < 4; fj++)
                    acc[c][fi][fj] = __builtin_amdgcn_mfma_f32_16x16x32_f16(a, bf[fj], acc[c][fi][fj], 0, 0, 0);
            }
        __syncthreads();
    }

    // fold: part[m] = sum over this wave's 64 j of relu(acc + ab1) * aw2 (fp32)
    int j0 = jh * 256 + w * 64;
    float ab1v[4], aw2v[4];
    #pragma unroll
    for (int fj = 0; fj < 4; fj++) {
        int j = j0 + fj * 16 + rl;
        ab1v[fj] = ab1[j];
        aw2v[fj] = aw2[j];
    }
    #pragma unroll
    for (int c = 0; c < 2; c++) {
        float part[2][4];
        #pragma unroll
        for (int fi = 0; fi < 2; fi++)
            #pragma unroll
            for (int r = 0; r < 4; r++) {
                float sv = 0.f;
                #pragma unroll
                for (int fj = 0; fj < 4; fj++)
                    sv += fmaxf(acc[c][fi][fj][r] + ab1v[fj], 0.f) * aw2v[fj];
                part[fi][r] = sv;
            }
        #pragma unroll
        for (int mask = 1; mask < 16; mask <<= 1)
            #pragma unroll
            for (int fi = 0; fi < 2; fi++)
                #pragma unroll
                for (int r = 0; r < 4; r++)
                    part[fi][r] += __shfl_xor(part[fi][r], mask);
        float myv = 0.f;
        #pragma unroll
        for (int fi = 0; fi < 2; fi++)
            #pragma unroll
            for (int r = 0; r < 4; r++)
                myv = (rl == fi * 4 + r) ? part[fi][r] : myv;
        if (rl < 8) {
            int m = (rl >> 2) * 16 + kg * 4 + (rl & 3);
            red[w][c][m] = myv;
        }
    }
    __syncthreads();

    if (t < 64) {
        int ci = t >> 5, m = t & 31;
        float s = red[0][ci][m] + red[1][ci][m] + red[2][ci][m] + red[3][ci][m];
        int gm = mhb * 32 + m;
        partial[((jh * 32 + b) * 64 + gm) * 36 + c0 + ci] = s;
    }
}

// ---------------- post-process: sum 2 jh partials, + ab2, masks, NEG_INF ------------
__global__ __launch_bounds__(256) void postproc(const float* __restrict__ partial,
                                                const float* __restrict__ mm,
                                                const float* __restrict__ cm,
                                                const float* __restrict__ ab2,
                                                float* __restrict__ out) {
    int i = blockIdx.x * 256 + threadIdx.x;  // < 73728
    int b = i / 2304;
    int rest = i - b * 2304;
    int m = rest / 36, c = rest - m * 36;
    float s = partial[(b * 64 + m) * 36 + c] + partial[((32 + b) * 64 + m) * 36 + c];
    float v = (s + ab2[0]) * mm[b * 64 + m] * cm[b * 36 + c];
    out[i] = (v != 0.f) ? v : NEG_INF_F;
}

extern "C" void kernel_launch(void* const* d_in, const int* in_sizes, int n_in,
                              void* d_out, int out_size, void* d_ws, size_t ws_size,
                              hipStream_t stream) {
    const float* ME  = (const float*)d_in[0];   // (32,64,1024)
    const float* CL  = (const float*)d_in[1];   // (32,36,1000)
    const float* MM  = (const float*)d_in[2];   // (32,64)
    const float* CM  = (const float*)d_in[3];   // (32,36)
    const float* VW1 = (const float*)d_in[4];   // (1000,512)
    const float* VB1 = (const float*)d_in[5];
    const float* VW2 = (const float*)d_in[6];   // (512,512)
    const float* VB2 = (const float*)d_in[7];
    const float* MW1 = (const float*)d_in[8];   // (1024,512)
    const float* MB1 = (const float*)d_in[9];
    const float* MW2 = (const float*)d_in[10];  // (512,512)
    const float* MB2 = (const float*)d_in[11];
    const float* AW1 = (const float*)d_in[12];  // (512,512)
    const float* AB1 = (const float*)d_in[13];
    const float* AW2 = (const float*)d_in[14];  // (512,1)
    const float* AB2 = (const float*)d_in[15];  // (1,)
    float* out = (float*)d_out;

    char* ws = (char*)d_ws;
    f16* me_h  = (f16*)ws; ws += (size_t)2048 * 1024 * 2;
    f16* cl_h  = (f16*)ws; ws += (size_t)1152 * 1024 * 2;
    f16* mw1t  = (f16*)ws; ws += (size_t)512 * 1024 * 2;
    f16* vw1t  = (f16*)ws; ws += (size_t)512 * 1024 * 2;
    f16* mw2t  = (f16*)ws; ws += (size_t)512 * 512 * 2;
    f16* vw2t  = (f16*)ws; ws += (size_t)512 * 512 * 2;
    f16* aw1t  = (f16*)ws; ws += (size_t)512 * 512 * 2;
    f16* men1  = (f16*)ws; ws += (size_t)2048 * 512 * 2;
    f16* menh  = (f16*)ws; ws += (size_t)2048 * 512 * 2;
    f16* vis1  = (f16*)ws; ws += (size_t)1152 * 512 * 2;
    f16* vish  = (f16*)ws; ws += (size_t)1152 * 512 * 2;
    float* part = (float*)ws; ws += (size_t)2 * 32 * 64 * 36 * 4;

    prep2<<<4992, 256, 0, stream>>>(ME, MW1, VW1, MW2, VW2, AW1, CL,
                                    me_h, mw1t, vw1t, mw2t, vw2t, aw1t, cl_h);
    gemm_stg<<<dim3(100, 16), 64, 0, stream>>>(me_h, cl_h, mw1t, vw1t, MB1, VB1,
                                               men1, vis1, 1024, 1);
    gemm_stg<<<dim3(100, 16), 64, 0, stream>>>(men1, vis1, mw2t, vw2t, MB2, VB2,
                                               menh, vish, 512, 0);
    attn_f9<<<dim3(18, 4, 32), 256, 0, stream>>>(menh, vish, aw1t, AB1, AW2, part);
    postproc<<<288, 256, 0, stream>>>(part, MM, CM, AB2, out);
}

// Round 18
// 87.551 us; speedup vs baseline: 1.6595x; 1.0867x over previous
//
#include <hip/hip_runtime.h>

typedef _Float16 f16;
typedef _Float16 f16x8 __attribute__((ext_vector_type(8)));
typedef _Float16 f16x4 __attribute__((ext_vector_type(4)));
typedef float f32x4 __attribute__((ext_vector_type(4)));
typedef float fl4 __attribute__((ext_vector_type(4)));

#define NEG_INF_F (-1e10f)

__device__ __forceinline__ void stage16(const f16* g, f16* l) {
    __builtin_amdgcn_global_load_lds((const __attribute__((address_space(1))) void*)g,
                                     (__attribute__((address_space(3))) void*)l, 16, 0, 0);
}

// ---------------- prep2: tiled transposes + conversions (unchanged, R11 win) -------
__global__ __launch_bounds__(256) void prep2(const float* __restrict__ me,
                                             const float* __restrict__ mw1,
                                             const float* __restrict__ vw1,
                                             const float* __restrict__ mw2,
                                             const float* __restrict__ vw2,
                                             const float* __restrict__ aw1,
                                             const float* __restrict__ cl,
                                             f16* __restrict__ me_h,
                                             f16* __restrict__ mw1t, f16* __restrict__ vw1t,
                                             f16* __restrict__ mw2t, f16* __restrict__ vw2t,
                                             f16* __restrict__ aw1t, f16* __restrict__ cl_h) {
    int bx = blockIdx.x, t = threadIdx.x;
    if (bx < 1792) {
        __shared__ float tile[32][33];
        const float* src; f16* dst; int Ksrc, Kp, tid;
        if (bx < 512)       { src = mw1; dst = mw1t; Ksrc = 1024; Kp = 1024; tid = bx; }
        else if (bx < 1024) { src = vw1; dst = vw1t; Ksrc = 1000; Kp = 1024; tid = bx - 512; }
        else if (bx < 1280) { src = mw2; dst = mw2t; Ksrc = 512;  Kp = 512;  tid = bx - 1024; }
        else if (bx < 1536) { src = vw2; dst = vw2t; Ksrc = 512;  Kp = 512;  tid = bx - 1280; }
        else                { src = aw1; dst = aw1t; Ksrc = 512;  Kp = 512;  tid = bx - 1536; }
        int tk = tid >> 4, tn = tid & 15;
        int x = t & 31, y = t >> 5;
        #pragma unroll
        for (int r = 0; r < 4; r++) {
            int k = tk * 32 + y * 4 + r;
            tile[y * 4 + r][x] = (k < Ksrc) ? src[k * 512 + tn * 32 + x] : 0.f;
        }
        __syncthreads();
        #pragma unroll
        for (int r = 0; r < 4; r++) {
            int n = tn * 32 + y * 4 + r;
            dst[n * Kp + tk * 32 + x] = (f16)tile[x][y * 4 + r];
        }
        return;
    }
    if (bx < 3840) {
        int i = (bx - 1792) * 256 + t;
        fl4 v = *(const fl4*)(me + i * 4);
        f16x4 h;
        #pragma unroll
        for (int e = 0; e < 4; e++) h[e] = (f16)v[e];
        *(f16x4*)(me_h + i * 4) = h;
        return;
    }
    {
        int i = (bx - 3840) * 256 + t;
        int idx = i * 4;
        int r = idx >> 10, k0 = idx & 1023;
        f16x4 h;
        if (k0 < 1000) {
            fl4 v = *(const fl4*)(cl + r * 1000 + k0);
            #pragma unroll
            for (int e = 0; e < 4; e++) h[e] = (f16)v[e];
        } else {
            #pragma unroll
            for (int e = 0; e < 4; e++) h[e] = (f16)0.f;
        }
        *(f16x4*)(cl_h + idx) = h;
    }
}

// ---------------- staged GEMM, 64x64 tile, 256 thr / 4 waves ----------
__global__ __launch_bounds__(256, 4) void gemm_stg2(const f16* __restrict__ Am,
                                                    const f16* __restrict__ Av,
                                                    const f16* __restrict__ Wm,
                                                    const f16* __restrict__ Wv,
                                                    const float* __restrict__ bm,
                                                    const float* __restrict__ bv,
                                                    f16* __restrict__ om,
                                                    f16* __restrict__ ov,
                                                    int K, int relu) {
    __shared__ f16 ab[2][2048], bb[2][2048];  // [buf][row 0..63][unit 0..3][8 f16]

    int t = threadIdx.x, lane = t & 63, w = t >> 6;
    int rl = lane & 15, kg = lane >> 4;
    int mq = w & 1, nq = w >> 1;
    bool isv = blockIdx.x >= 32;
    int mb = isv ? blockIdx.x - 32 : blockIdx.x;
    const f16* A = isv ? Av : Am;
    const f16* Wt = isv ? Wv : Wm;
    const float* bias = isv ? bv : bm;
    f16* out = isv ? ov : om;
    int m0 = mb * 64, n0 = blockIdx.y * 64;
    int pu = kg ^ ((rl >> 1) & 3);

    int srow = t >> 2;                       // 0..63
    int sk8 = (t & 3) ^ ((srow >> 1) & 3);
    const f16* a_src = A + (m0 + srow) * K + sk8 * 8;
    const f16* b_src = Wt + (n0 + srow) * K + sk8 * 8;
    int nsteps = K >> 5;

    f32x4 acc[2][2] = {};

    stage16(a_src, &ab[0][t * 8]);
    stage16(b_src, &bb[0][t * 8]);
    __syncthreads();

    for (int s = 0; s < nsteps; s++) {
        int cur = s & 1;
        if (s + 1 < nsteps) {
            int k1 = (s + 1) * 32;
            stage16(a_src + k1, &ab[cur ^ 1][t * 8]);
            stage16(b_src + k1, &bb[cur ^ 1][t * 8]);
        }
        f16x8 af[2], bf[2];
        #pragma unroll
        for (int f = 0; f < 2; f++) {
            af[f] = *(const f16x8*)&ab[cur][((mq * 32 + f * 16 + rl) * 4 + pu) * 8];
            bf[f] = *(const f16x8*)&bb[cur][((nq * 32 + f * 16 + rl) * 4 + pu) * 8];
        }
        #pragma unroll
        for (int fi = 0; fi < 2; fi++)
            #pragma unroll
            for (int fj = 0; fj < 2; fj++)
                acc[fi][fj] = __builtin_amdgcn_mfma_f32_16x16x32_f16(af[fi], bf[fj], acc[fi][fj], 0, 0, 0);
        __syncthreads();
    }

    #pragma unroll
    for (int fi = 0; fi < 2; fi++)
        #pragma unroll
        for (int fj = 0; fj < 2; fj++) {
            int col = n0 + nq * 32 + fj * 16 + rl;
            float bv2 = bias[col];
            #pragma unroll
            for (int r = 0; r < 4; r++) {
                int row = m0 + mq * 32 + fi * 16 + kg * 4 + r;
                float v = acc[fi][fj][r] + bv2;
                if (relu) v = fmaxf(v, 0.f);
                out[row * 512 + col] = (f16)v;
            }
        }
}

// ---------------- fused attention f10: f8 wave tile, mh merged (aw shared) ----------
// grid (9 cq, 4 jh, 32 b) = 1152 blocks, 512 thr (8 waves = 2mh x 4js), bounds(512,4).
// Block = 4c x 64m x 128j x K=512. Per BK=32 step: stage aw 128x32 (8KB, shared by both
// m-halves) + men 64x32 (4KB) dbuf; vis 4c staged once (4KB). Wave reads mm[2]+bf[2]
// (4 swizzled ds_read_b128) + vv[4] broadcast -> 8 builds, 16 MFMAs. Zero global loads
// in K loop. aw traffic halved vs f8 (295->147MB). Partials -> scratch; postproc sums.
__global__ __launch_bounds__(512, 4) void attn_f10(const f16* __restrict__ men,
                                                   const f16* __restrict__ vis,
                                                   const f16* __restrict__ aw1t,
                                                   const float* __restrict__ ab1,
                                                   const float* __restrict__ aw2,
                                                   float* __restrict__ partial) {
    __shared__ f16 awb[2][4096];    // [buf][row 0..127][unit 0..3][8 f16], swizzled
    __shared__ f16 mnb[2][2048];    // [buf][row 0..63][unit][8], swizzled
    __shared__ f16 vist[2048];      // [c 0..3][k 0..511], staged once
    __shared__ float red[4][4][64]; // [js][c][m]

    int t = threadIdx.x, lane = t & 63, w = t >> 6;
    int mh = w & 1, js = w >> 1;
    int cq = blockIdx.x, jh = blockIdx.y, b = blockIdx.z;
    int c0 = cq * 4;
    int rl = lane & 15, kg = lane >> 4;
    int pu = kg ^ ((rl >> 1) & 3);

    int srow = t >> 2;                       // 0..127
    int sk8 = (t & 3) ^ ((srow >> 1) & 3);
    const f16* aw_src = aw1t + (jh * 128 + srow) * 512 + sk8 * 8;
    const f16* mn_src = men + (b * 64 + srow) * 512 + sk8 * 8;          // t<256 (srow<64)
    const f16* vi_src = vis + (b * 36 + c0 + (t >> 6)) * 512 + (t & 63) * 8;  // t<256

    f32x4 acc[4][2][2] = {};   // [c][fi][fj]

    // prologue: stage vis (once) + step0 into buf 0
    if (t < 256) {
        stage16(vi_src, &vist[t * 8]);
        stage16(mn_src, &mnb[0][t * 8]);
    }
    stage16(aw_src, &awb[0][t * 8]);
    __syncthreads();

    for (int s = 0; s < 16; s++) {
        int cur = s & 1;
        if (s < 15) {  // issue next step's staging FIRST
            int k1 = (s + 1) * 32;
            stage16(aw_src + k1, &awb[cur ^ 1][t * 8]);
            if (t < 256)
                stage16(mn_src + k1, &mnb[cur ^ 1][t * 8]);
        }

        f16x8 mm[2], bf[2], vv[4];
        #pragma unroll
        for (int f = 0; f < 2; f++) {
            mm[f] = *(const f16x8*)&mnb[cur][((mh * 32 + f * 16 + rl) * 4 + pu) * 8];
            bf[f] = *(const f16x8*)&awb[cur][((js * 32 + f * 16 + rl) * 4 + pu) * 8];
        }
        #pragma unroll
        for (int c = 0; c < 4; c++)
            vv[c] = *(const f16x8*)&vist[c * 512 + s * 32 + kg * 8];  // broadcast

        #pragma unroll
        for (int fi = 0; fi < 2; fi++)
            #pragma unroll
            for (int c = 0; c < 4; c++) {
                f16x8 a = mm[fi] * vv[c];   // packed f16 multiply
                #pragma unroll
                for (int fj = 0; fj < 2; fj++)
                    acc[c][fi][fj] = __builtin_amdgcn_mfma_f32_16x16x32_f16(a, bf[fj], acc[c][fi][fj], 0, 0, 0);
            }
        __syncthreads();
    }

    // fold: part[m] = sum over this wave's 32 j of relu(acc + ab1) * aw2 (fp32)
    int j0 = jh * 128 + js * 32;
    float ab1v[2], aw2v[2];
    #pragma unroll
    for (int fj = 0; fj < 2; fj++) {
        int j = j0 + fj * 16 + rl;
        ab1v[fj] = ab1[j];
        aw2v[fj] = aw2[j];
    }
    #pragma unroll
    for (int c = 0; c < 4; c++) {
        float part[2][4];
        #pragma unroll
        for (int fi = 0; fi < 2; fi++)
            #pragma unroll
            for (int r = 0; r < 4; r++) {
                float sv = 0.f;
                #pragma unroll
                for (int fj = 0; fj < 2; fj++)
                    sv += fmaxf(acc[c][fi][fj][r] + ab1v[fj], 0.f) * aw2v[fj];
                part[fi][r] = sv;
            }
        #pragma unroll
        for (int mask = 1; mask < 16; mask <<= 1)
            #pragma unroll
            for (int fi = 0; fi < 2; fi++)
                #pragma unroll
                for (int r = 0; r < 4; r++)
                    part[fi][r] += __shfl_xor(part[fi][r], mask);
        float myv = 0.f;
        #pragma unroll
        for (int fi = 0; fi < 2; fi++)
            #pragma unroll
            for (int r = 0; r < 4; r++)
                myv = (rl == fi * 4 + r) ? part[fi][r] : myv;
        if (rl < 8) {
            int m = (rl >> 2) * 16 + kg * 4 + (rl & 3);
            red[js][c][mh * 32 + m] = myv;
        }
    }
    __syncthreads();

    if (t < 256) {
        int ci = t >> 6, m = t & 63;
        float s = red[0][ci][m] + red[1][ci][m] + red[2][ci][m] + red[3][ci][m];
        partial[((jh * 32 + b) * 64 + m) * 36 + c0 + ci] = s;
    }
}

// ---------------- post-process: sum 4 jh partials, + ab2, masks, NEG_INF ------------
__global__ __launch_bounds__(256) void postproc(const float* __restrict__ partial,
                                                const float* __restrict__ mm,
                                                const float* __restrict__ cm,
                                                const float* __restrict__ ab2,
                                                float* __restrict__ out) {
    int i = blockIdx.x * 256 + threadIdx.x;  // < 73728
    int b = i / 2304;
    int rest = i - b * 2304;
    int m = rest / 36, c = rest - m * 36;
    float s = 0.f;
    #pragma unroll
    for (int jh = 0; jh < 4; jh++)
        s += partial[((jh * 32 + b) * 64 + m) * 36 + c];
    float v = (s + ab2[0]) * mm[b * 64 + m] * cm[b * 36 + c];
    out[i] = (v != 0.f) ? v : NEG_INF_F;
}

extern "C" void kernel_launch(void* const* d_in, const int* in_sizes, int n_in,
                              void* d_out, int out_size, void* d_ws, size_t ws_size,
                              hipStream_t stream) {
    const float* ME  = (const float*)d_in[0];   // (32,64,1024)
    const float* CL  = (const float*)d_in[1];   // (32,36,1000)
    const float* MM  = (const float*)d_in[2];   // (32,64)
    const float* CM  = (const float*)d_in[3];   // (32,36)
    const float* VW1 = (const float*)d_in[4];   // (1000,512)
    const float* VB1 = (const float*)d_in[5];
    const float* VW2 = (const float*)d_in[6];   // (512,512)
    const float* VB2 = (const float*)d_in[7];
    const float* MW1 = (const float*)d_in[8];   // (1024,512)
    const float* MB1 = (const float*)d_in[9];
    const float* MW2 = (const float*)d_in[10];  // (512,512)
    const float* MB2 = (const float*)d_in[11];
    const float* AW1 = (const float*)d_in[12];  // (512,512)
    const float* AB1 = (const float*)d_in[13];
    const float* AW2 = (const float*)d_in[14];  // (512,1)
    const float* AB2 = (const float*)d_in[15];  // (1,)
    float* out = (float*)d_out;

    char* ws = (char*)d_ws;
    f16* me_h  = (f16*)ws; ws += (size_t)2048 * 1024 * 2;
    f16* cl_h  = (f16*)ws; ws += (size_t)1152 * 1024 * 2;
    f16* mw1t  = (f16*)ws; ws += (size_t)512 * 1024 * 2;
    f16* vw1t  = (f16*)ws; ws += (size_t)512 * 1024 * 2;
    f16* mw2t  = (f16*)ws; ws += (size_t)512 * 512 * 2;
    f16* vw2t  = (f16*)ws; ws += (size_t)512 * 512 * 2;
    f16* aw1t  = (f16*)ws; ws += (size_t)512 * 512 * 2;
    f16* men1  = (f16*)ws; ws += (size_t)2048 * 512 * 2;
    f16* menh  = (f16*)ws; ws += (size_t)2048 * 512 * 2;
    f16* vis1  = (f16*)ws; ws += (size_t)1152 * 512 * 2;
    f16* vish  = (f16*)ws; ws += (size_t)1152 * 512 * 2;
    float* part = (float*)ws; ws += (size_t)4 * 32 * 64 * 36 * 4;

    prep2<<<4992, 256, 0, stream>>>(ME, MW1, VW1, MW2, VW2, AW1, CL,
                                    me_h, mw1t, vw1t, mw2t, vw2t, aw1t, cl_h);
    gemm_stg2<<<dim3(50, 8), 256, 0, stream>>>(me_h, cl_h, mw1t, vw1t, MB1, VB1,
                                               men1, vis1, 1024, 1);
    gemm_stg2<<<dim3(50, 8), 256, 0, stream>>>(men1, vis1, mw2t, vw2t, MB2, VB2,
                                               menh, vish, 512, 0);
    attn_f10<<<dim3(9, 4, 32), 512, 0, stream>>>(menh, vish, aw1t, AB1, AW2, part);
    postproc<<<288, 256, 0, stream>>>(part, MM, CM, AB2, out);
}

// Round 19
// 77.978 us; speedup vs baseline: 1.8632x; 1.1228x over previous
//
#include <hip/hip_runtime.h>

typedef _Float16 f16;
typedef _Float16 f16x8 __attribute__((ext_vector_type(8)));
typedef _Float16 f16x4 __attribute__((ext_vector_type(4)));
typedef float f32x4 __attribute__((ext_vector_type(4)));
typedef float fl4 __attribute__((ext_vector_type(4)));

#define NEG_INF_F (-1e10f)

__device__ __forceinline__ void stage16(const f16* g, f16* l) {
    __builtin_amdgcn_global_load_lds((const __attribute__((address_space(1))) void*)g,
                                     (__attribute__((address_space(3))) void*)l, 16, 0, 0);
}

// ---------------- prep2: tiled transposes + conversions (unchanged) -------
__global__ __launch_bounds__(256) void prep2(const float* __restrict__ me,
                                             const float* __restrict__ mw1,
                                             const float* __restrict__ vw1,
                                             const float* __restrict__ mw2,
                                             const float* __restrict__ vw2,
                                             const float* __restrict__ aw1,
                                             const float* __restrict__ cl,
                                             f16* __restrict__ me_h,
                                             f16* __restrict__ mw1t, f16* __restrict__ vw1t,
                                             f16* __restrict__ mw2t, f16* __restrict__ vw2t,
                                             f16* __restrict__ aw1t, f16* __restrict__ cl_h) {
    int bx = blockIdx.x, t = threadIdx.x;
    if (bx < 1792) {
        __shared__ float tile[32][33];
        const float* src; f16* dst; int Ksrc, Kp, tid;
        if (bx < 512)       { src = mw1; dst = mw1t; Ksrc = 1024; Kp = 1024; tid = bx; }
        else if (bx < 1024) { src = vw1; dst = vw1t; Ksrc = 1000; Kp = 1024; tid = bx - 512; }
        else if (bx < 1280) { src = mw2; dst = mw2t; Ksrc = 512;  Kp = 512;  tid = bx - 1024; }
        else if (bx < 1536) { src = vw2; dst = vw2t; Ksrc = 512;  Kp = 512;  tid = bx - 1280; }
        else                { src = aw1; dst = aw1t; Ksrc = 512;  Kp = 512;  tid = bx - 1536; }
        int tk = tid >> 4, tn = tid & 15;
        int x = t & 31, y = t >> 5;
        #pragma unroll
        for (int r = 0; r < 4; r++) {
            int k = tk * 32 + y * 4 + r;
            tile[y * 4 + r][x] = (k < Ksrc) ? src[k * 512 + tn * 32 + x] : 0.f;
        }
        __syncthreads();
        #pragma unroll
        for (int r = 0; r < 4; r++) {
            int n = tn * 32 + y * 4 + r;
            dst[n * Kp + tk * 32 + x] = (f16)tile[x][y * 4 + r];
        }
        return;
    }
    if (bx < 3840) {
        int i = (bx - 1792) * 256 + t;
        fl4 v = *(const fl4*)(me + i * 4);
        f16x4 h;
        #pragma unroll
        for (int e = 0; e < 4; e++) h[e] = (f16)v[e];
        *(f16x4*)(me_h + i * 4) = h;
        return;
    }
    {
        int i = (bx - 3840) * 256 + t;
        int idx = i * 4;
        int r = idx >> 10, k0 = idx & 1023;
        f16x4 h;
        if (k0 < 1000) {
            fl4 v = *(const fl4*)(cl + r * 1000 + k0);
            #pragma unroll
            for (int e = 0; e < 4; e++) h[e] = (f16)v[e];
        } else {
            #pragma unroll
            for (int e = 0; e < 4; e++) h[e] = (f16)0.f;
        }
        *(f16x4*)(cl_h + idx) = h;
    }
}

// ---------------- staged GEMM, 64x64 tile, 256 thr / 4 waves (unchanged) ----------
__global__ __launch_bounds__(256, 4) void gemm_stg2(const f16* __restrict__ Am,
                                                    const f16* __restrict__ Av,
                                                    const f16* __restrict__ Wm,
                                                    const f16* __restrict__ Wv,
                                                    const float* __restrict__ bm,
                                                    const float* __restrict__ bv,
                                                    f16* __restrict__ om,
                                                    f16* __restrict__ ov,
                                                    int K, int relu) {
    __shared__ f16 ab[2][2048], bb[2][2048];

    int t = threadIdx.x, lane = t & 63, w = t >> 6;
    int rl = lane & 15, kg = lane >> 4;
    int mq = w & 1, nq = w >> 1;
    bool isv = blockIdx.x >= 32;
    int mb = isv ? blockIdx.x - 32 : blockIdx.x;
    const f16* A = isv ? Av : Am;
    const f16* Wt = isv ? Wv : Wm;
    const float* bias = isv ? bv : bm;
    f16* out = isv ? ov : om;
    int m0 = mb * 64, n0 = blockIdx.y * 64;
    int pu = kg ^ ((rl >> 1) & 3);

    int srow = t >> 2;
    int sk8 = (t & 3) ^ ((srow >> 1) & 3);
    const f16* a_src = A + (m0 + srow) * K + sk8 * 8;
    const f16* b_src = Wt + (n0 + srow) * K + sk8 * 8;
    int nsteps = K >> 5;

    f32x4 acc[2][2] = {};

    stage16(a_src, &ab[0][t * 8]);
    stage16(b_src, &bb[0][t * 8]);
    __syncthreads();

    for (int s = 0; s < nsteps; s++) {
        int cur = s & 1;
        if (s + 1 < nsteps) {
            int k1 = (s + 1) * 32;
            stage16(a_src + k1, &ab[cur ^ 1][t * 8]);
            stage16(b_src + k1, &bb[cur ^ 1][t * 8]);
        }
        f16x8 af[2], bf[2];
        #pragma unroll
        for (int f = 0; f < 2; f++) {
            af[f] = *(const f16x8*)&ab[cur][((mq * 32 + f * 16 + rl) * 4 + pu) * 8];
            bf[f] = *(const f16x8*)&bb[cur][((nq * 32 + f * 16 + rl) * 4 + pu) * 8];
        }
        #pragma unroll
        for (int fi = 0; fi < 2; fi++)
            #pragma unroll
            for (int fj = 0; fj < 2; fj++)
                acc[fi][fj] = __builtin_amdgcn_mfma_f32_16x16x32_f16(af[fi], bf[fj], acc[fi][fj], 0, 0, 0);
        __syncthreads();
    }

    #pragma unroll
    for (int fi = 0; fi < 2; fi++)
        #pragma unroll
        for (int fj = 0; fj < 2; fj++) {
            int col = n0 + nq * 32 + fj * 16 + rl;
            float bv2 = bias[col];
            #pragma unroll
            for (int r = 0; r < 4; r++) {
                int row = m0 + mq * 32 + fi * 16 + kg * 4 + r;
                float v = acc[fi][fj][r] + bv2;
                if (relu) v = fmaxf(v, 0.f);
                out[row * 512 + col] = (f16)v;
            }
        }
}

// ---------------- fused attention f11: fi=1, c=4, fj=4 (builds halved vs f10) -------
// grid (9 cq, 4 jh, 32 b) = 1152 blocks, 512 thr (8 waves = 4ms x 2jq), bounds(512,4).
// Block = 4c x 64m x 128j x K=512. Staging IDENTICAL to f10 (aw 8KB + mn 4KB dbuf,
// vist 4KB once). Wave = 16m (fi=1) x 64j (fj=4) x 4c: per step 4 builds (16 pk_mul,
// ~32cyc) -> 16 MFMAs (~80cyc); reads mm[1]+bf[4] swizzled + vv[4] broadcast.
// acc[c][fj] = 64 VGPRs. Partials -> scratch; postproc sums 4 jh.
__global__ __launch_bounds__(512, 4) void attn_f11(const f16* __restrict__ men,
                                                   const f16* __restrict__ vis,
                                                   const f16* __restrict__ aw1t,
                                                   const float* __restrict__ ab1,
                                                   const float* __restrict__ aw2,
                                                   float* __restrict__ partial) {
    __shared__ f16 awb[2][4096];    // [buf][row j 0..127][unit 0..3][8 f16], swizzled
    __shared__ f16 mnb[2][2048];    // [buf][row m 0..63][unit][8], swizzled
    __shared__ f16 vist[2048];      // [c 0..3][k 0..511], staged once
    __shared__ float red[2][4][64]; // [jq][c][m]

    int t = threadIdx.x, lane = t & 63, w = t >> 6;
    int ms = w & 3, jq = w >> 2;
    int cq = blockIdx.x, jh = blockIdx.y, b = blockIdx.z;
    int c0 = cq * 4;
    int rl = lane & 15, kg = lane >> 4;
    int pu = kg ^ ((rl >> 1) & 3);

    int srow = t >> 2;                       // 0..127
    int sk8 = (t & 3) ^ ((srow >> 1) & 3);
    const f16* aw_src = aw1t + (jh * 128 + srow) * 512 + sk8 * 8;
    const f16* mn_src = men + (b * 64 + srow) * 512 + sk8 * 8;          // t<256 (srow<64)
    const f16* vi_src = vis + (b * 36 + c0 + (t >> 6)) * 512 + (t & 63) * 8;  // t<256

    f32x4 acc[4][4] = {};   // [c][fj]

    // prologue: stage vis (once) + step0 into buf 0
    if (t < 256) {
        stage16(vi_src, &vist[t * 8]);
        stage16(mn_src, &mnb[0][t * 8]);
    }
    stage16(aw_src, &awb[0][t * 8]);
    __syncthreads();

    for (int s = 0; s < 16; s++) {
        int cur = s & 1;
        if (s < 15) {  // issue next step's staging FIRST
            int k1 = (s + 1) * 32;
            stage16(aw_src + k1, &awb[cur ^ 1][t * 8]);
            if (t < 256)
                stage16(mn_src + k1, &mnb[cur ^ 1][t * 8]);
        }

        f16x8 mm, bf[4], vv[4];
        mm = *(const f16x8*)&mnb[cur][((ms * 16 + rl) * 4 + pu) * 8];
        #pragma unroll
        for (int fj = 0; fj < 4; fj++)
            bf[fj] = *(const f16x8*)&awb[cur][((jq * 64 + fj * 16 + rl) * 4 + pu) * 8];
        #pragma unroll
        for (int c = 0; c < 4; c++)
            vv[c] = *(const f16x8*)&vist[c * 512 + s * 32 + kg * 8];  // broadcast

        #pragma unroll
        for (int c = 0; c < 4; c++) {
            f16x8 a = mm * vv[c];   // 4 pk_mul -> feeds 4 MFMAs
            #pragma unroll
            for (int fj = 0; fj < 4; fj++)
                acc[c][fj] = __builtin_amdgcn_mfma_f32_16x16x32_f16(a, bf[fj], acc[c][fj], 0, 0, 0);
        }
        __syncthreads();
    }

    // fold: part[m] = sum over this wave's 64 j of relu(acc + ab1) * aw2 (fp32)
    int j0 = jh * 128 + jq * 64;
    float ab1v[4], aw2v[4];
    #pragma unroll
    for (int fj = 0; fj < 4; fj++) {
        int j = j0 + fj * 16 + rl;
        ab1v[fj] = ab1[j];
        aw2v[fj] = aw2[j];
    }
    #pragma unroll
    for (int c = 0; c < 4; c++) {
        float part[4];
        #pragma unroll
        for (int r = 0; r < 4; r++) {
            float sv = 0.f;
            #pragma unroll
            for (int fj = 0; fj < 4; fj++)
                sv += fmaxf(acc[c][fj][r] + ab1v[fj], 0.f) * aw2v[fj];
            part[r] = sv;
        }
        #pragma unroll
        for (int mask = 1; mask < 16; mask <<= 1)
            #pragma unroll
            for (int r = 0; r < 4; r++)
                part[r] += __shfl_xor(part[r], mask);
        float myv = 0.f;
        #pragma unroll
        for (int r = 0; r < 4; r++)
            myv = (rl == r) ? part[r] : myv;
        if (rl < 4) {
            int m = ms * 16 + kg * 4 + rl;
            red[jq][c][m] = myv;
        }
    }
    __syncthreads();

    if (t < 256) {
        int ci = t >> 6, m = t & 63;
        float s = red[0][ci][m] + red[1][ci][m];
        partial[((jh * 32 + b) * 64 + m) * 36 + c0 + ci] = s;
    }
}

// ---------------- post-process: sum 4 jh partials, + ab2, masks, NEG_INF ------------
__global__ __launch_bounds__(256) void postproc(const float* __restrict__ partial,
                                                const float* __restrict__ mm,
                                                const float* __restrict__ cm,
                                                const float* __restrict__ ab2,
                                                float* __restrict__ out) {
    int i = blockIdx.x * 256 + threadIdx.x;  // < 73728
    int b = i / 2304;
    int rest = i - b * 2304;
    int m = rest / 36, c = rest - m * 36;
    float s = 0.f;
    #pragma unroll
    for (int jh = 0; jh < 4; jh++)
        s += partial[((jh * 32 + b) * 64 + m) * 36 + c];
    float v = (s + ab2[0]) * mm[b * 64 + m] * cm[b * 36 + c];
    out[i] = (v != 0.f) ? v : NEG_INF_F;
}

extern "C" void kernel_launch(void* const* d_in, const int* in_sizes, int n_in,
                              void* d_out, int out_size, void* d_ws, size_t ws_size,
                              hipStream_t stream) {
    const float* ME  = (const float*)d_in[0];   // (32,64,1024)
    const float* CL  = (const float*)d_in[1];   // (32,36,1000)
    const float* MM  = (const float*)d_in[2];   // (32,64)
    const float* CM  = (const float*)d_in[3];   // (32,36)
    const float* VW1 = (const float*)d_in[4];   // (1000,512)
    const float* VB1 = (const float*)d_in[5];
    const float* VW2 = (const float*)d_in[6];   // (512,512)
    const float* VB2 = (const float*)d_in[7];
    const float* MW1 = (const float*)d_in[8];   // (1024,512)
    const float* MB1 = (const float*)d_in[9];
    const float* MW2 = (const float*)d_in[10];  // (512,512)
    const float* MB2 = (const float*)d_in[11];
    const float* AW1 = (const float*)d_in[12];  // (512,512)
    const float* AB1 = (const float*)d_in[13];
    const float* AW2 = (const float*)d_in[14];  // (512,1)
    const float* AB2 = (const float*)d_in[15];  // (1,)
    float* out = (float*)d_out;

    char* ws = (char*)d_ws;
    f16* me_h  = (f16*)ws; ws += (size_t)2048 * 1024 * 2;
    f16* cl_h  = (f16*)ws; ws += (size_t)1152 * 1024 * 2;
    f16* mw1t  = (f16*)ws; ws += (size_t)512 * 1024 * 2;
    f16* vw1t  = (f16*)ws; ws += (size_t)512 * 1024 * 2;
    f16* mw2t  = (f16*)ws; ws += (size_t)512 * 512 * 2;
    f16* vw2t  = (f16*)ws; ws += (size_t)512 * 512 * 2;
    f16* aw1t  = (f16*)ws; ws += (size_t)512 * 512 * 2;
    f16* men1  = (f16*)ws; ws += (size_t)2048 * 512 * 2;
    f16* menh  = (f16*)ws; ws += (size_t)2048 * 512 * 2;
    f16* vis1  = (f16*)ws; ws += (size_t)1152 * 512 * 2;
    f16* vish  = (f16*)ws; ws += (size_t)1152 * 512 * 2;
    float* part = (float*)ws; ws += (size_t)4 * 32 * 64 * 36 * 4;

    prep2<<<4992, 256, 0, stream>>>(ME, MW1, VW1, MW2, VW2, AW1, CL,
                                    me_h, mw1t, vw1t, mw2t, vw2t, aw1t, cl_h);
    gemm_stg2<<<dim3(50, 8), 256, 0, stream>>>(me_h, cl_h, mw1t, vw1t, MB1, VB1,
                                               men1, vis1, 1024, 1);
    gemm_stg2<<<dim3(50, 8), 256, 0, stream>>>(men1, vis1, mw2t, vw2t, MB2, VB2,
                                               menh, vish, 512, 0);
    attn_f11<<<dim3(9, 4, 32), 512, 0, stream>>>(menh, vish, aw1t, AB1, AW2, part);
    postproc<<<288, 256, 0, stream>>>(part, MM, CM, AB2, out);
}

// Round 21
// 77.167 us; speedup vs baseline: 1.8828x; 1.0105x over previous
//
#include <hip/hip_runtime.h>

typedef _Float16 f16;
typedef _Float16 f16x8 __attribute__((ext_vector_type(8)));
typedef _Float16 f16x4 __attribute__((ext_vector_type(4)));
typedef float f32x4 __attribute__((ext_vector_type(4)));
typedef float fl4 __attribute__((ext_vector_type(4)));

#define NEG_INF_F (-1e10f)

__device__ __forceinline__ void stage16(const f16* g, f16* l) {
    __builtin_amdgcn_global_load_lds((const __attribute__((address_space(1))) void*)g,
                                     (__attribute__((address_space(3))) void*)l, 16, 0, 0);
}

// ---------------- prep2: tiled transposes + conversions (unchanged) -------
__global__ __launch_bounds__(256) void prep2(const float* __restrict__ me,
                                             const float* __restrict__ mw1,
                                             const float* __restrict__ vw1,
                                             const float* __restrict__ mw2,
                                             const float* __restrict__ vw2,
                                             const float* __restrict__ aw1,
                                             const float* __restrict__ cl,
                                             f16* __restrict__ me_h,
                                             f16* __restrict__ mw1t, f16* __restrict__ vw1t,
                                             f16* __restrict__ mw2t, f16* __restrict__ vw2t,
                                             f16* __restrict__ aw1t, f16* __restrict__ cl_h) {
    int bx = blockIdx.x, t = threadIdx.x;
    if (bx < 1792) {
        __shared__ float tile[32][33];
        const float* src; f16* dst; int Ksrc, Kp, tid;
        if (bx < 512)       { src = mw1; dst = mw1t; Ksrc = 1024; Kp = 1024; tid = bx; }
        else if (bx < 1024) { src = vw1; dst = vw1t; Ksrc = 1000; Kp = 1024; tid = bx - 512; }
        else if (bx < 1280) { src = mw2; dst = mw2t; Ksrc = 512;  Kp = 512;  tid = bx - 1024; }
        else if (bx < 1536) { src = vw2; dst = vw2t; Ksrc = 512;  Kp = 512;  tid = bx - 1280; }
        else                { src = aw1; dst = aw1t; Ksrc = 512;  Kp = 512;  tid = bx - 1536; }
        int tk = tid >> 4, tn = tid & 15;
        int x = t & 31, y = t >> 5;
        #pragma unroll
        for (int r = 0; r < 4; r++) {
            int k = tk * 32 + y * 4 + r;
            tile[y * 4 + r][x] = (k < Ksrc) ? src[k * 512 + tn * 32 + x] : 0.f;
        }
        __syncthreads();
        #pragma unroll
        for (int r = 0; r < 4; r++) {
            int n = tn * 32 + y * 4 + r;
            dst[n * Kp + tk * 32 + x] = (f16)tile[x][y * 4 + r];
        }
        return;
    }
    if (bx < 3840) {
        int i = (bx - 1792) * 256 + t;
        fl4 v = *(const fl4*)(me + i * 4);
        f16x4 h;
        #pragma unroll
        for (int e = 0; e < 4; e++) h[e] = (f16)v[e];
        *(f16x4*)(me_h + i * 4) = h;
        return;
    }
    {
        int i = (bx - 3840) * 256 + t;
        int idx = i * 4;
        int r = idx >> 10, k0 = idx & 1023;
        f16x4 h;
        if (k0 < 1000) {
            fl4 v = *(const fl4*)(cl + r * 1000 + k0);
            #pragma unroll
            for (int e = 0; e < 4; e++) h[e] = (f16)v[e];
        } else {
            #pragma unroll
            for (int e = 0; e < 4; e++) h[e] = (f16)0.f;
        }
        *(f16x4*)(cl_h + idx) = h;
    }
}

// ---------------- staged GEMM, 64x64 tile, 256 thr / 4 waves (unchanged) ----------
__global__ __launch_bounds__(256, 4) void gemm_stg2(const f16* __restrict__ Am,
                                                    const f16* __restrict__ Av,
                                                    const f16* __restrict__ Wm,
                                                    const f16* __restrict__ Wv,
                                                    const float* __restrict__ bm,
                                                    const float* __restrict__ bv,
                                                    f16* __restrict__ om,
                                                    f16* __restrict__ ov,
                                                    int K, int relu) {
    __shared__ f16 ab[2][2048], bb[2][2048];

    int t = threadIdx.x, lane = t & 63, w = t >> 6;
    int rl = lane & 15, kg = lane >> 4;
    int mq = w & 1, nq = w >> 1;
    bool isv = blockIdx.x >= 32;
    int mb = isv ? blockIdx.x - 32 : blockIdx.x;
    const f16* A = isv ? Av : Am;
    const f16* Wt = isv ? Wv : Wm;
    const float* bias = isv ? bv : bm;
    f16* out = isv ? ov : om;
    int m0 = mb * 64, n0 = blockIdx.y * 64;
    int pu = kg ^ ((rl >> 1) & 3);

    int srow = t >> 2;
    int sk8 = (t & 3) ^ ((srow >> 1) & 3);
    const f16* a_src = A + (m0 + srow) * K + sk8 * 8;
    const f16* b_src = Wt + (n0 + srow) * K + sk8 * 8;
    int nsteps = K >> 5;

    f32x4 acc[2][2] = {};

    stage16(a_src, &ab[0][t * 8]);
    stage16(b_src, &bb[0][t * 8]);
    __syncthreads();

    for (int s = 0; s < nsteps; s++) {
        int cur = s & 1;
        if (s + 1 < nsteps) {
            int k1 = (s + 1) * 32;
            stage16(a_src + k1, &ab[cur ^ 1][t * 8]);
            stage16(b_src + k1, &bb[cur ^ 1][t * 8]);
        }
        f16x8 af[2], bf[2];
        #pragma unroll
        for (int f = 0; f < 2; f++) {
            af[f] = *(const f16x8*)&ab[cur][((mq * 32 + f * 16 + rl) * 4 + pu) * 8];
            bf[f] = *(const f16x8*)&bb[cur][((nq * 32 + f * 16 + rl) * 4 + pu) * 8];
        }
        #pragma unroll
        for (int fi = 0; fi < 2; fi++)
            #pragma unroll
            for (int fj = 0; fj < 2; fj++)
                acc[fi][fj] = __builtin_amdgcn_mfma_f32_16x16x32_f16(af[fi], bf[fj], acc[fi][fj], 0, 0, 0);
        __syncthreads();
    }

    #pragma unroll
    for (int fi = 0; fi < 2; fi++)
        #pragma unroll
        for (int fj = 0; fj < 2; fj++) {
            int col = n0 + nq * 32 + fj * 16 + rl;
            float bv2 = bias[col];
            #pragma unroll
            for (int r = 0; r < 4; r++) {
                int row = m0 + mq * 32 + fi * 16 + kg * 4 + r;
                float v = acc[fi][fj][r] + bv2;
                if (relu) v = fmaxf(v, 0.f);
                out[row * 512 + col] = (f16)v;
            }
        }
}

// ---------------- fused attention f12: f11 tile + 3-buffer counted-vmcnt pipeline ---
// grid (9 cq, 4 jh, 32 b), 512 thr (8 waves = 4ms x 2jq), bounds(512,3). LDS 42KB.
// T3/T4: batch for step s+2 issued right after step-s barrier -> each load has ~2
// steps (>300cyc) to land; s_waitcnt vmcnt(2|1) (counted, never 0 mid-loop) + raw
// s_barrier replaces __syncthreads' vmcnt(0) drain. Waves 0-3 stage aw+mn (2/batch),
// waves 4-7 aw only (1/batch). lgkm ordering implicit (all ds_reads feed MFMAs).
__global__ __launch_bounds__(512, 3) void attn_f12(const f16* __restrict__ men,
                                                   const f16* __restrict__ vis,
                                                   const f16* __restrict__ aw1t,
                                                   const float* __restrict__ ab1,
                                                   const float* __restrict__ aw2,
                                                   float* __restrict__ partial) {
    __shared__ f16 awb[3][4096];    // [buf][row j 0..127][unit 0..3][8 f16], swizzled
    __shared__ f16 mnb[3][2048];    // [buf][row m 0..63][unit][8], swizzled
    __shared__ f16 vist[2048];      // [c 0..3][k 0..511], staged once
    __shared__ float red[2][4][64]; // [jq][c][m]

    int t = threadIdx.x, lane = t & 63, w = t >> 6;
    int ms = w & 3, jq = w >> 2;
    int cq = blockIdx.x, jh = blockIdx.y, b = blockIdx.z;
    int c0 = cq * 4;
    int rl = lane & 15, kg = lane >> 4;
    int pu = kg ^ ((rl >> 1) & 3);
    bool w4 = (w < 4);   // == (t < 256)

    int srow = t >> 2;                       // 0..127
    int sk8 = (t & 3) ^ ((srow >> 1) & 3);
    const f16* aw_src = aw1t + (jh * 128 + srow) * 512 + sk8 * 8;
    const f16* mn_src = men + (b * 64 + srow) * 512 + sk8 * 8;            // w4 only
    const f16* vi_src = vis + (b * 36 + c0 + (t >> 6)) * 512 + (t & 63) * 8;  // w4 only

    f32x4 acc[4][4] = {};   // [c][fj]

    // prologue: vist + batches 0,1 (issue order matters for vmcnt counting)
    if (w4) stage16(vi_src, &vist[t * 8]);
    stage16(aw_src, &awb[0][t * 8]);
    if (w4) stage16(mn_src, &mnb[0][t * 8]);
    stage16(aw_src + 32, &awb[1][t * 8]);
    if (w4) stage16(mn_src + 32, &mnb[1][t * 8]);
    // retire vist + batch0 (outstanding <= batch1 = 2|1)
    if (w4) asm volatile("s_waitcnt vmcnt(2)" ::: "memory");
    else    asm volatile("s_waitcnt vmcnt(1)" ::: "memory");
    __builtin_amdgcn_s_barrier();
    __builtin_amdgcn_sched_barrier(0);

    #pragma unroll
    for (int s = 0; s < 16; s++) {
        if (s > 0) {
            // retire batch s (outstanding <= batch s+1)
            if (s == 15)  asm volatile("s_waitcnt vmcnt(0)" ::: "memory");
            else if (w4)  asm volatile("s_waitcnt vmcnt(2)" ::: "memory");
            else          asm volatile("s_waitcnt vmcnt(1)" ::: "memory");
            __builtin_amdgcn_s_barrier();
            __builtin_amdgcn_sched_barrier(0);
        }
        // issue batch s+2 EARLY (lands during steps s, s+1)
        if (s <= 13) {
            int k2 = (s + 2) * 32;
            stage16(aw_src + k2, &awb[(s + 2) % 3][t * 8]);
            if (w4) stage16(mn_src + k2, &mnb[(s + 2) % 3][t * 8]);
        }

        const int cur = s % 3;
        f16x8 mm, bf[4], vv[4];
        mm = *(const f16x8*)&mnb[cur][((ms * 16 + rl) * 4 + pu) * 8];
        #pragma unroll
        for (int fj = 0; fj < 4; fj++)
            bf[fj] = *(const f16x8*)&awb[cur][((jq * 64 + fj * 16 + rl) * 4 + pu) * 8];
        #pragma unroll
        for (int c = 0; c < 4; c++)
            vv[c] = *(const f16x8*)&vist[c * 512 + s * 32 + kg * 8];  // broadcast

        #pragma unroll
        for (int c = 0; c < 4; c++) {
            f16x8 a = mm * vv[c];   // 4 pk_mul -> feeds 4 MFMAs
            #pragma unroll
            for (int fj = 0; fj < 4; fj++)
                acc[c][fj] = __builtin_amdgcn_mfma_f32_16x16x32_f16(a, bf[fj], acc[c][fj], 0, 0, 0);
        }
    }

    // fold: part[m] = sum over this wave's 64 j of relu(acc + ab1) * aw2 (fp32)
    int j0 = jh * 128 + jq * 64;
    float ab1v[4], aw2v[4];
    #pragma unroll
    for (int fj = 0; fj < 4; fj++) {
        int j = j0 + fj * 16 + rl;
        ab1v[fj] = ab1[j];
        aw2v[fj] = aw2[j];
    }
    #pragma unroll
    for (int c = 0; c < 4; c++) {
        float part[4];
        #pragma unroll
        for (int r = 0; r < 4; r++) {
            float sv = 0.f;
            #pragma unroll
            for (int fj = 0; fj < 4; fj++)
                sv += fmaxf(acc[c][fj][r] + ab1v[fj], 0.f) * aw2v[fj];
            part[r] = sv;
        }
        #pragma unroll
        for (int mask = 1; mask < 16; mask <<= 1)
            #pragma unroll
            for (int r = 0; r < 4; r++)
                part[r] += __shfl_xor(part[r], mask);
        float myv = 0.f;
        #pragma unroll
        for (int r = 0; r < 4; r++)
            myv = (rl == r) ? part[r] : myv;
        if (rl < 4) {
            int m = ms * 16 + kg * 4 + rl;
            red[jq][c][m] = myv;
        }
    }
    __syncthreads();

    if (t < 256) {
        int ci = t >> 6, m = t & 63;
        float s = red[0][ci][m] + red[1][ci][m];
        partial[((jh * 32 + b) * 64 + m) * 36 + c0 + ci] = s;
    }
}

// ---------------- post-process: sum 4 jh partials, + ab2, masks, NEG_INF ------------
__global__ __launch_bounds__(256) void postproc(const float* __restrict__ partial,
                                                const float* __restrict__ mm,
                                                const float* __restrict__ cm,
                                                const float* __restrict__ ab2,
                                                float* __restrict__ out) {
    int i = blockIdx.x * 256 + threadIdx.x;  // < 73728
    int b = i / 2304;
    int rest = i - b * 2304;
    int m = rest / 36, c = rest - m * 36;
    float s = 0.f;
    #pragma unroll
    for (int jh = 0; jh < 4; jh++)
        s += partial[((jh * 32 + b) * 64 + m) * 36 + c];
    float v = (s + ab2[0]) * mm[b * 64 + m] * cm[b * 36 + c];
    out[i] = (v != 0.f) ? v : NEG_INF_F;
}

extern "C" void kernel_launch(void* const* d_in, const int* in_sizes, int n_in,
                              void* d_out, int out_size, void* d_ws, size_t ws_size,
                              hipStream_t stream) {
    const float* ME  = (const float*)d_in[0];   // (32,64,1024)
    const float* CL  = (const float*)d_in[1];   // (32,36,1000)
    const float* MM  = (const float*)d_in[2];   // (32,64)
    const float* CM  = (const float*)d_in[3];   // (32,36)
    const float* VW1 = (const float*)d_in[4];   // (1000,512)
    const float* VB1 = (const float*)d_in[5];
    const float* VW2 = (const float*)d_in[6];   // (512,512)
    const float* VB2 = (const float*)d_in[7];
    const float* MW1 = (const float*)d_in[8];   // (1024,512)
    const float* MB1 = (const float*)d_in[9];
    const float* MW2 = (const float*)d_in[10];  // (512,512)
    const float* MB2 = (const float*)d_in[11];
    const float* AW1 = (const float*)d_in[12];  // (512,512)
    const float* AB1 = (const float*)d_in[13];
    const float* AW2 = (const float*)d_in[14];  // (512,1)
    const float* AB2 = (const float*)d_in[15];  // (1,)
    float* out = (float*)d_out;

    char* ws = (char*)d_ws;
    f16* me_h  = (f16*)ws; ws += (size_t)2048 * 1024 * 2;
    f16* cl_h  = (f16*)ws; ws += (size_t)1152 * 1024 * 2;
    f16* mw1t  = (f16*)ws; ws += (size_t)512 * 1024 * 2;
    f16* vw1t  = (f16*)ws; ws += (size_t)512 * 1024 * 2;
    f16* mw2t  = (f16*)ws; ws += (size_t)512 * 512 * 2;
    f16* vw2t  = (f16*)ws; ws += (size_t)512 * 512 * 2;
    f16* aw1t  = (f16*)ws; ws += (size_t)512 * 512 * 2;
    f16* men1  = (f16*)ws; ws += (size_t)2048 * 512 * 2;
    f16* menh  = (f16*)ws; ws += (size_t)2048 * 512 * 2;
    f16* vis1  = (f16*)ws; ws += (size_t)1152 * 512 * 2;
    f16* vish  = (f16*)ws; ws += (size_t)1152 * 512 * 2;
    float* part = (float*)ws; ws += (size_t)4 * 32 * 64 * 36 * 4;

    prep2<<<4992, 256, 0, stream>>>(ME, MW1, VW1, MW2, VW2, AW1, CL,
                                    me_h, mw1t, vw1t, mw2t, vw2t, aw1t, cl_h);
    gemm_stg2<<<dim3(50, 8), 256, 0, stream>>>(me_h, cl_h, mw1t, vw1t, MB1, VB1,
                                               men1, vis1, 1024, 1);
    gemm_stg2<<<dim3(50, 8), 256, 0, stream>>>(men1, vis1, mw2t, vw2t, MB2, VB2,
                                               menh, vish, 512, 0);
    attn_f12<<<dim3(9, 4, 32), 512, 0, stream>>>(menh, vish, aw1t, AB1, AW2, part);
    postproc<<<288, 256, 0, stream>>>(part, MM, CM, AB2, out);
}